// Round 1
// baseline (760.879 us; speedup 1.0000x reference)
//
#include <hip/hip_runtime.h>
#include <stdint.h>

// ---------------------------------------------------------------------------
// Differential attention, bf16 MFMA pipeline.
// B=2 T=2048 C=2048 H=8 HD=256 HALF=128
// ---------------------------------------------------------------------------

typedef __bf16 bf16;
typedef bf16 bf16x8 __attribute__((ext_vector_type(8)));
typedef bf16 bf16x4 __attribute__((ext_vector_type(4)));
typedef bf16 bf16x2 __attribute__((ext_vector_type(2)));
typedef float f32x4 __attribute__((ext_vector_type(4)));

typedef void __attribute__((address_space(1)))* gas_t;
typedef void __attribute__((address_space(3)))* las_t;

// async global->LDS, 16B per lane. LDS dest must be wave-uniform base; HW adds lane*16.
__device__ __forceinline__ void gload16(const void* g, void* l) {
  __builtin_amdgcn_global_load_lds((gas_t)(uintptr_t)g, (las_t)(uint32_t)(uintptr_t)l, 16, 0, 0);
}

__device__ __forceinline__ f32x4 mfma16x16(bf16x8 a, bf16x8 b, f32x4 c) {
  return __builtin_amdgcn_mfma_f32_16x16x32_bf16(a, b, c, 0, 0, 0);
}

// ---------------- cast fp32 -> bf16, 4 elems/thread ----------------
__global__ __launch_bounds__(256) void cast_f32_bf16(const float* __restrict__ in,
                                                     bf16* __restrict__ out, int n4) {
  int i = blockIdx.x * 256 + threadIdx.x;
  if (i >= n4) return;
  float4 v = ((const float4*)in)[i];
  bf16x4 o;
  o[0] = (bf16)v.x; o[1] = (bf16)v.y; o[2] = (bf16)v.z; o[3] = (bf16)v.w;
  ((bf16x4*)out)[i] = o;
}

// ---------------- lambda scalar ----------------
__global__ void lambda_kernel(const float* __restrict__ lq1, const float* __restrict__ lk1,
                              const float* __restrict__ lq2, const float* __restrict__ lk2,
                              float* __restrict__ out) {
  __shared__ float red[8];
  int tid = threadIdx.x;  // 256 threads, arrays are 256 long
  float a = lq1[tid] * lk1[tid];
  float b = lq2[tid] * lk2[tid];
#pragma unroll
  for (int m = 32; m >= 1; m >>= 1) {
    a += __shfl_xor(a, m, 64);
    b += __shfl_xor(b, m, 64);
  }
  if ((tid & 63) == 0) { red[tid >> 6] = a; red[4 + (tid >> 6)] = b; }
  __syncthreads();
  if (tid == 0) {
    float s1 = red[0] + red[1] + red[2] + red[3];
    float s2 = red[4] + red[5] + red[6] + red[7];
    out[0] = expf(s1) - expf(s2) + 0.8f;
  }
}

// ---------------- RMS norm over contiguous 128-chunks, in place ----------------
// one wave per 128-vector; outscale folds the attention 1/sqrt(128) into q.
__global__ __launch_bounds__(256) void rmsnorm128(bf16* __restrict__ buf, float outscale) {
  int tid = threadIdx.x;
  int wid = tid >> 6, lane = tid & 63;
  size_t vec = (size_t)blockIdx.x * 4 + wid;
  bf16* p = buf + vec * 128 + lane * 2;
  bf16x2 v = *(bf16x2*)p;
  float a = (float)v[0], b = (float)v[1];
  float s = a * a + b * b;
#pragma unroll
  for (int m = 32; m >= 1; m >>= 1) s += __shfl_xor(s, m, 64);
  float r = rsqrtf(s * (1.0f / 128.0f) + 1.1920929e-07f) * outscale;
  v[0] = (bf16)(a * r);
  v[1] = (bf16)(b * r);
  *(bf16x2*)p = v;
}

// ---------------- NT GEMM: C[M,N] = A[M,K] @ B[N,K]^T (both row-major bf16) ----------
// 128x128 tile, BK=32, 4 waves (2x2 of 64x64), fragment-ordered LDS so all
// ds_read_b128 are contiguous 1024B wave reads (conflict-free).
// MODE 0: bf16 C[row*N+col]. MODE 1: bf16 transposed vT[b][col][t] (row=b*2048+t).
// MODE 2: f32 C[row*N+col] * scale.
template <int MODE>
__global__ __launch_bounds__(256) void gemm_nt(const bf16* __restrict__ A, const bf16* __restrict__ B,
                                               void* __restrict__ Cp, int N, int K, float scale) {
  __shared__ char lds[16384];
  char* ldsA = lds;
  char* ldsB = lds + 8192;
  const int tid = threadIdx.x;
  const int wid = tid >> 6, lane = tid & 63;
  const int l15 = lane & 15, lhi = lane >> 4;
  const int bm = blockIdx.y * 128, bn = blockIdx.x * 128;
  const int wm = (wid >> 1) * 64, wn = (wid & 1) * 64;

  const f32x4 fz = {0.f, 0.f, 0.f, 0.f};
  f32x4 acc[4][4];
#pragma unroll
  for (int m = 0; m < 4; ++m)
#pragma unroll
    for (int n = 0; n < 4; ++n) acc[m][n] = fz;

  // staging: chunk id = i*256 + tid -> group g = i*4+wid (uniform/wave), lane chunk.
  // group g holds rows g*16..g*16+15; lane l: row g*16+(l&15), k-chunk (l>>4)*8.
  const bf16* aSrc0 = A + (size_t)(bm + wid * 16 + l15) * K + lhi * 8;
  const bf16* aSrc1 = A + (size_t)(bm + 64 + wid * 16 + l15) * K + lhi * 8;
  const bf16* bSrc0 = B + (size_t)(bn + wid * 16 + l15) * K + lhi * 8;
  const bf16* bSrc1 = B + (size_t)(bn + 64 + wid * 16 + l15) * K + lhi * 8;
  char* aDst0 = ldsA + wid * 1024;
  char* aDst1 = ldsA + 4096 + wid * 1024;
  char* bDst0 = ldsB + wid * 1024;
  char* bDst1 = ldsB + 4096 + wid * 1024;

  const int gA = wm >> 4;  // 0 or 4
  const int gB = wn >> 4;  // 0 or 4

  for (int k0 = 0; k0 < K; k0 += 32) {
    gload16(aSrc0 + k0, aDst0);
    gload16(aSrc1 + k0, aDst1);
    gload16(bSrc0 + k0, bDst0);
    gload16(bSrc1 + k0, bDst1);
    __syncthreads();
    bf16x8 af[4], bfr[4];
#pragma unroll
    for (int m = 0; m < 4; ++m) af[m] = *(const bf16x8*)(ldsA + ((gA + m) * 64 + lane) * 16);
#pragma unroll
    for (int n = 0; n < 4; ++n) bfr[n] = *(const bf16x8*)(ldsB + ((gB + n) * 64 + lane) * 16);
#pragma unroll
    for (int m = 0; m < 4; ++m)
#pragma unroll
      for (int n = 0; n < 4; ++n) acc[m][n] = mfma16x16(af[m], bfr[n], acc[m][n]);
    __syncthreads();
  }

#pragma unroll
  for (int m = 0; m < 4; ++m) {
#pragma unroll
    for (int n = 0; n < 4; ++n) {
#pragma unroll
      for (int r = 0; r < 4; ++r) {
        int row = bm + wm + m * 16 + lhi * 4 + r;  // C/D: col=lane&15, row=(lane>>4)*4+r
        int col = bn + wn + n * 16 + l15;
        float v = acc[m][n][r];
        if (MODE == 0) {
          ((bf16*)Cp)[(size_t)row * N + col] = (bf16)v;
        } else if (MODE == 1) {
          int bb = row >> 11, t = row & 2047;
          ((bf16*)Cp)[(size_t)bb * 2048 * 2048 + (size_t)col * 2048 + t] = (bf16)v;
        } else {
          ((float*)Cp)[(size_t)row * N + col] = v * scale;
        }
      }
    }
  }
}

// ---------------- dual-stream causal flash attention ----------------
// grid (32 qtiles, 16 b*h); 4 waves, each owns 16 q-rows. KV tile = 32.
// qb/kb: [4096][2048] bf16 normed (q pre-scaled by 1/sqrt(128)); vtb: [2][2048 d][2048 t].
// yb out: [4096][2048] bf16 = y1 - lambda*y2.
__global__ __launch_bounds__(256) void attn_kernel(const bf16* __restrict__ qb, const bf16* __restrict__ kb,
                                                   const bf16* __restrict__ vtb, bf16* __restrict__ yb,
                                                   const float* __restrict__ lamp) {
  __shared__ char lds[36864];
  char* k1l = lds;              // 8KB  [32 t][128 d] frag-ordered
  char* k2l = lds + 8192;       // 8KB
  char* vtl = lds + 16384;      // 16KB [256 d][32 t] frag-ordered
  const int tid = threadIdx.x;
  const int wid = tid >> 6, lane = tid & 63;
  const int l15 = lane & 15, lhi = lane >> 4;
  char* pl = lds + 32768 + wid * 1024;  // per-wave P buffer [16][32] bf16
  const int qt = blockIdx.x;
  const int bh = blockIdx.y;
  const int b = bh >> 3, h = bh & 7;
  const int qr0 = qt * 64 + wid * 16;
  const float lam = lamp[0];

  // Q fragments in registers (both halves), k-index = (lane>>4)*8+j
  const bf16* qrow = qb + (size_t)(b * 2048 + qr0 + l15) * 2048 + h * 256 + lhi * 8;
  bf16x8 q1f[4], q2f[4];
#pragma unroll
  for (int s = 0; s < 4; ++s) {
    q1f[s] = *(const bf16x8*)(qrow + s * 32);
    q2f[s] = *(const bf16x8*)(qrow + 128 + s * 32);
  }

  const f32x4 fz = {0.f, 0.f, 0.f, 0.f};
  f32x4 y1[16], y2[16];
#pragma unroll
  for (int f = 0; f < 16; ++f) { y1[f] = fz; y2[f] = fz; }
  float m1[4], l1[4], m2[4], l2[4];
#pragma unroll
  for (int r = 0; r < 4; ++r) { m1[r] = -1e30f; l1[r] = 0.f; m2[r] = -1e30f; l2[r] = 0.f; }

  const int nkt = 2 * qt + 2;
  const bf16* kbase = kb + (size_t)(b * 2048) * 2048 + h * 256;
  const bf16* vbase = vtb + (size_t)b * 2048 * 2048;

  for (int kt = 0; kt < nkt; ++kt) {
    const int t0 = kt * 32;
    // stage K1,K2: chunk gs=i*4+wid -> t-group i, kstep wid
#pragma unroll
    for (int i = 0; i < 2; ++i) {
      const bf16* sp = kbase + (size_t)(t0 + i * 16 + l15) * 2048 + wid * 32 + lhi * 8;
      gload16(sp, k1l + i * 4096 + wid * 1024);
      gload16(sp + 128, k2l + i * 4096 + wid * 1024);
    }
    // stage VT: frag f=i*4+wid holds d-cols f*16..f*16+15, t-chunk (lane>>4)*8
#pragma unroll
    for (int i = 0; i < 4; ++i) {
      int f = i * 4 + wid;
      const bf16* vp = vbase + (size_t)(h * 256 + f * 16 + l15) * 2048 + t0 + lhi * 8;
      gload16(vp, vtl + f * 1024);
    }
    __syncthreads();
    if (t0 <= qr0 + 15) {  // wave-uniform: tile not fully masked for this wave
      f32x4 s1g[2], s2g[2];
#pragma unroll
      for (int g = 0; g < 2; ++g) {
        f32x4 a1 = fz, a2 = fz;
#pragma unroll
        for (int s = 0; s < 4; ++s) {
          a1 = mfma16x16(q1f[s], *(const bf16x8*)(k1l + ((g * 4 + s) * 64 + lane) * 16), a1);
          a2 = mfma16x16(q2f[s], *(const bf16x8*)(k2l + ((g * 4 + s) * 64 + lane) * 16), a2);
        }
        s1g[g] = a1;
        s2g[g] = a2;
      }
      if (t0 + 31 > qr0) {  // diagonal: apply causal mask
#pragma unroll
        for (int g = 0; g < 2; ++g) {
          int col = t0 + g * 16 + l15;
#pragma unroll
          for (int r = 0; r < 4; ++r) {
            int row = qr0 + lhi * 4 + r;
            if (col > row) { s1g[g][r] = -1e30f; s2g[g][r] = -1e30f; }
          }
        }
      }
      // ---- stream 1: online softmax + PV ----
      {
        float fct[4];
#pragma unroll
        for (int r = 0; r < 4; ++r) {
          float mx = fmaxf(s1g[0][r], s1g[1][r]);
          mx = fmaxf(mx, __shfl_xor(mx, 1, 64));
          mx = fmaxf(mx, __shfl_xor(mx, 2, 64));
          mx = fmaxf(mx, __shfl_xor(mx, 4, 64));
          mx = fmaxf(mx, __shfl_xor(mx, 8, 64));
          float mn = fmaxf(m1[r], mx);
          fct[r] = __expf(m1[r] - mn);
          m1[r] = mn;
          float p0 = __expf(s1g[0][r] - mn);
          float p1 = __expf(s1g[1][r] - mn);
          float rs = p0 + p1;
          rs += __shfl_xor(rs, 1, 64);
          rs += __shfl_xor(rs, 2, 64);
          rs += __shfl_xor(rs, 4, 64);
          rs += __shfl_xor(rs, 8, 64);
          l1[r] = l1[r] * fct[r] + rs;
          s1g[0][r] = p0;
          s1g[1][r] = p1;
        }
#pragma unroll
        for (int g = 0; g < 2; ++g)
#pragma unroll
          for (int r = 0; r < 4; ++r)
            *(bf16*)(pl + ((lhi * 4 + r) * 32 + g * 16 + l15) * 2) = (bf16)s1g[g][r];
#pragma unroll
        for (int f = 0; f < 16; ++f) {
          y1[f][0] *= fct[0]; y1[f][1] *= fct[1]; y1[f][2] *= fct[2]; y1[f][3] *= fct[3];
        }
        bf16x8 pa = *(const bf16x8*)(pl + (l15 * 32 + lhi * 8) * 2);
#pragma unroll
        for (int f = 0; f < 16; ++f)
          y1[f] = mfma16x16(pa, *(const bf16x8*)(vtl + (f * 64 + lane) * 16), y1[f]);
      }
      // ---- stream 2 ----
      {
        float fct[4];
#pragma unroll
        for (int r = 0; r < 4; ++r) {
          float mx = fmaxf(s2g[0][r], s2g[1][r]);
          mx = fmaxf(mx, __shfl_xor(mx, 1, 64));
          mx = fmaxf(mx, __shfl_xor(mx, 2, 64));
          mx = fmaxf(mx, __shfl_xor(mx, 4, 64));
          mx = fmaxf(mx, __shfl_xor(mx, 8, 64));
          float mn = fmaxf(m2[r], mx);
          fct[r] = __expf(m2[r] - mn);
          m2[r] = mn;
          float p0 = __expf(s2g[0][r] - mn);
          float p1 = __expf(s2g[1][r] - mn);
          float rs = p0 + p1;
          rs += __shfl_xor(rs, 1, 64);
          rs += __shfl_xor(rs, 2, 64);
          rs += __shfl_xor(rs, 4, 64);
          rs += __shfl_xor(rs, 8, 64);
          l2[r] = l2[r] * fct[r] + rs;
          s2g[0][r] = p0;
          s2g[1][r] = p1;
        }
#pragma unroll
        for (int g = 0; g < 2; ++g)
#pragma unroll
          for (int r = 0; r < 4; ++r)
            *(bf16*)(pl + ((lhi * 4 + r) * 32 + g * 16 + l15) * 2) = (bf16)s2g[g][r];
#pragma unroll
        for (int f = 0; f < 16; ++f) {
          y2[f][0] *= fct[0]; y2[f][1] *= fct[1]; y2[f][2] *= fct[2]; y2[f][3] *= fct[3];
        }
        bf16x8 pa = *(const bf16x8*)(pl + (l15 * 32 + lhi * 8) * 2);
#pragma unroll
        for (int f = 0; f < 16; ++f)
          y2[f] = mfma16x16(pa, *(const bf16x8*)(vtl + (f * 64 + lane) * 16), y2[f]);
      }
    }
    __syncthreads();
  }

  // epilogue: y = y1/l1 - lam*y2/l2 -> yb[b*2048+row][h*256+d]
#pragma unroll
  for (int r = 0; r < 4; ++r) {
    float inv1 = 1.f / l1[r];
    float inv2 = lam / l2[r];
    int row = qr0 + lhi * 4 + r;
    bf16* orow = yb + (size_t)(b * 2048 + row) * 2048 + h * 256 + l15;
#pragma unroll
    for (int f = 0; f < 16; ++f) {
      float v = y1[f][r] * inv1 - y2[f][r] * inv2;
      orow[f * 16] = (bf16)v;
    }
  }
}

// ---------------------------------------------------------------------------
extern "C" void kernel_launch(void* const* d_in, const int* in_sizes, int n_in,
                              void* d_out, int out_size, void* d_ws, size_t ws_size,
                              hipStream_t stream) {
  const float* x = (const float*)d_in[0];
  const float* wq = (const float*)d_in[1];
  const float* wk = (const float*)d_in[2];
  const float* wv = (const float*)d_in[3];
  const float* wo = (const float*)d_in[4];
  const float* lq1 = (const float*)d_in[5];
  const float* lk1 = (const float*)d_in[6];
  const float* lq2 = (const float*)d_in[7];
  const float* lk2 = (const float*)d_in[8];
  float* out = (float*)d_out;
  char* ws = (char*)d_ws;

  if (ws_size < 117440516) return;  // need ~112 MB scratch

  bf16* xb = (bf16*)(ws + 0);             // [4096][2048]
  bf16* wqb = (bf16*)(ws + 16777216);     // [2048][2048]
  bf16* wkb = (bf16*)(ws + 25165824);
  bf16* wvb = (bf16*)(ws + 33554432);
  bf16* wob = (bf16*)(ws + 41943040);
  bf16* qbuf = (bf16*)(ws + 50331648);    // [4096][2048]
  bf16* kbuf = (bf16*)(ws + 67108864);    // [4096][2048]
  bf16* vtb = (bf16*)(ws + 83886080);     // [2][2048 d][2048 t]
  bf16* ybuf = (bf16*)(ws + 100663296);   // [4096][2048]
  float* lam = (float*)(ws + 117440512);

  cast_f32_bf16<<<8192, 256, 0, stream>>>(x, xb, 2097152);
  cast_f32_bf16<<<4096, 256, 0, stream>>>(wq, wqb, 1048576);
  cast_f32_bf16<<<4096, 256, 0, stream>>>(wk, wkb, 1048576);
  cast_f32_bf16<<<4096, 256, 0, stream>>>(wv, wvb, 1048576);
  cast_f32_bf16<<<4096, 256, 0, stream>>>(wo, wob, 1048576);
  lambda_kernel<<<1, 256, 0, stream>>>(lq1, lk1, lq2, lk2, lam);

  dim3 gg(16, 32);  // N/128, M/128
  gemm_nt<0><<<gg, 256, 0, stream>>>(xb, wqb, qbuf, 2048, 2048, 1.f);
  gemm_nt<0><<<gg, 256, 0, stream>>>(xb, wkb, kbuf, 2048, 2048, 1.f);
  gemm_nt<1><<<gg, 256, 0, stream>>>(xb, wvb, vtb, 2048, 2048, 1.f);

  rmsnorm128<<<16384, 256, 0, stream>>>(qbuf, 0.08838834764831845f);  // fold 1/sqrt(128)
  rmsnorm128<<<16384, 256, 0, stream>>>(kbuf, 1.0f);

  attn_kernel<<<dim3(32, 16), 256, 0, stream>>>(qbuf, kbuf, vtb, ybuf, lam);

  gemm_nt<2><<<gg, 256, 0, stream>>>(ybuf, wob, out, 2048, 2048, 0.2f);
}

// Round 2
// 468.812 us; speedup vs baseline: 1.6230x; 1.6230x over previous
//
#include <hip/hip_runtime.h>
#include <stdint.h>

// ---------------------------------------------------------------------------
// Differential attention, bf16 MFMA pipeline.
// B=2 T=2048 C=2048 H=8 HD=256 HALF=128
// ---------------------------------------------------------------------------

typedef __bf16 bf16;
typedef bf16 bf16x8 __attribute__((ext_vector_type(8)));
typedef bf16 bf16x4 __attribute__((ext_vector_type(4)));
typedef bf16 bf16x2 __attribute__((ext_vector_type(2)));
typedef float f32x4 __attribute__((ext_vector_type(4)));

typedef void __attribute__((address_space(1)))* gas_t;
typedef void __attribute__((address_space(3)))* las_t;

// async global->LDS, 16B per lane. LDS dest must be wave-uniform base; HW adds lane*16.
__device__ __forceinline__ void gload16(const void* g, void* l) {
  __builtin_amdgcn_global_load_lds((gas_t)(uintptr_t)g, (las_t)(uint32_t)(uintptr_t)l, 16, 0, 0);
}

__device__ __forceinline__ f32x4 mfma16x16(bf16x8 a, bf16x8 b, f32x4 c) {
  return __builtin_amdgcn_mfma_f32_16x16x32_bf16(a, b, c, 0, 0, 0);
}

// ---------------- cast fp32 -> bf16, 4 elems/thread ----------------
__global__ __launch_bounds__(256) void cast_f32_bf16(const float* __restrict__ in,
                                                     bf16* __restrict__ out, int n4) {
  int i = blockIdx.x * 256 + threadIdx.x;
  if (i >= n4) return;
  float4 v = ((const float4*)in)[i];
  bf16x4 o;
  o[0] = (bf16)v.x; o[1] = (bf16)v.y; o[2] = (bf16)v.z; o[3] = (bf16)v.w;
  ((bf16x4*)out)[i] = o;
}

// ---------------- lambda scalar ----------------
__global__ void lambda_kernel(const float* __restrict__ lq1, const float* __restrict__ lk1,
                              const float* __restrict__ lq2, const float* __restrict__ lk2,
                              float* __restrict__ out) {
  __shared__ float red[8];
  int tid = threadIdx.x;  // 256 threads, arrays are 256 long
  float a = lq1[tid] * lk1[tid];
  float b = lq2[tid] * lk2[tid];
#pragma unroll
  for (int m = 32; m >= 1; m >>= 1) {
    a += __shfl_xor(a, m, 64);
    b += __shfl_xor(b, m, 64);
  }
  if ((tid & 63) == 0) { red[tid >> 6] = a; red[4 + (tid >> 6)] = b; }
  __syncthreads();
  if (tid == 0) {
    float s1 = red[0] + red[1] + red[2] + red[3];
    float s2 = red[4] + red[5] + red[6] + red[7];
    out[0] = expf(s1) - expf(s2) + 0.8f;
  }
}

// ---------------- RMS norm over contiguous 128-chunks, in place ----------------
__global__ __launch_bounds__(256) void rmsnorm128(bf16* __restrict__ buf, float outscale) {
  int tid = threadIdx.x;
  int wid = tid >> 6, lane = tid & 63;
  size_t vec = (size_t)blockIdx.x * 4 + wid;
  bf16* p = buf + vec * 128 + lane * 2;
  bf16x2 v = *(bf16x2*)p;
  float a = (float)v[0], b = (float)v[1];
  float s = a * a + b * b;
#pragma unroll
  for (int m = 32; m >= 1; m >>= 1) s += __shfl_xor(s, m, 64);
  float r = rsqrtf(s * (1.0f / 128.0f) + 1.1920929e-07f) * outscale;
  v[0] = (bf16)(a * r);
  v[1] = (bf16)(b * r);
  *(bf16x2*)p = v;
}

// ---------------- NT GEMM: C[M,N] = A[M,K] @ B[N,K]^T ----------
// 128x128 tile, BK=32, 4 waves (2x2 of 64x64), fragment-ordered LDS.
template <int MODE>
__global__ __launch_bounds__(256) void gemm_nt(const bf16* __restrict__ A, const bf16* __restrict__ B,
                                               void* __restrict__ Cp, int N, int K, float scale) {
  __shared__ char lds[16384];
  char* ldsA = lds;
  char* ldsB = lds + 8192;
  const int tid = threadIdx.x;
  const int wid = tid >> 6, lane = tid & 63;
  const int l15 = lane & 15, lhi = lane >> 4;
  const int bm = blockIdx.y * 128, bn = blockIdx.x * 128;
  const int wm = (wid >> 1) * 64, wn = (wid & 1) * 64;

  const f32x4 fz = {0.f, 0.f, 0.f, 0.f};
  f32x4 acc[4][4];
#pragma unroll
  for (int m = 0; m < 4; ++m)
#pragma unroll
    for (int n = 0; n < 4; ++n) acc[m][n] = fz;

  const bf16* aSrc0 = A + (size_t)(bm + wid * 16 + l15) * K + lhi * 8;
  const bf16* aSrc1 = A + (size_t)(bm + 64 + wid * 16 + l15) * K + lhi * 8;
  const bf16* bSrc0 = B + (size_t)(bn + wid * 16 + l15) * K + lhi * 8;
  const bf16* bSrc1 = B + (size_t)(bn + 64 + wid * 16 + l15) * K + lhi * 8;
  char* aDst0 = ldsA + wid * 1024;
  char* aDst1 = ldsA + 4096 + wid * 1024;
  char* bDst0 = ldsB + wid * 1024;
  char* bDst1 = ldsB + 4096 + wid * 1024;

  const int gA = wm >> 4;
  const int gB = wn >> 4;

  for (int k0 = 0; k0 < K; k0 += 32) {
    gload16(aSrc0 + k0, aDst0);
    gload16(aSrc1 + k0, aDst1);
    gload16(bSrc0 + k0, bDst0);
    gload16(bSrc1 + k0, bDst1);
    __syncthreads();
    bf16x8 af[4], bfr[4];
#pragma unroll
    for (int m = 0; m < 4; ++m) af[m] = *(const bf16x8*)(ldsA + ((gA + m) * 64 + lane) * 16);
#pragma unroll
    for (int n = 0; n < 4; ++n) bfr[n] = *(const bf16x8*)(ldsB + ((gB + n) * 64 + lane) * 16);
#pragma unroll
    for (int m = 0; m < 4; ++m)
#pragma unroll
      for (int n = 0; n < 4; ++n) acc[m][n] = mfma16x16(af[m], bfr[n], acc[m][n]);
    __syncthreads();
  }

#pragma unroll
  for (int m = 0; m < 4; ++m) {
#pragma unroll
    for (int n = 0; n < 4; ++n) {
#pragma unroll
      for (int r = 0; r < 4; ++r) {
        int row = bm + wm + m * 16 + lhi * 4 + r;
        int col = bn + wn + n * 16 + l15;
        float v = acc[m][n][r];
        if (MODE == 0) {
          ((bf16*)Cp)[(size_t)row * N + col] = (bf16)v;
        } else if (MODE == 1) {
          int bb = row >> 11, t = row & 2047;
          ((bf16*)Cp)[(size_t)bb * 2048 * 2048 + (size_t)col * 2048 + t] = (bf16)v;
        } else {
          ((float*)Cp)[(size_t)row * N + col] = v * scale;
        }
      }
    }
  }
}

// ---------------- dual-stream causal flash attention, v2 ----------------
// Fixed-max softmax (scores bounded by sqrt(128)<12 since q,k are rms-normed and
// q carries 1/sqrt(128)): p = exp(s-12), no cross-lane max/sum in the loop,
// per-lane l accumulation, epilogue reduce. K double-buffered; all staging
// deferred to after barrier2 so it hides under the next QK+exp phase.
// grid (16 bh, 32 qt) with qt reversed (longest blocks dispatch first).
__global__ __launch_bounds__(256) void attn_kernel(const bf16* __restrict__ qb, const bf16* __restrict__ kb,
                                                   const bf16* __restrict__ vtb, bf16* __restrict__ yb,
                                                   const float* __restrict__ lamp) {
  __shared__ char lds[57344];
  // K ping p: lds + p*16384 (K1 8KB, K2 8KB). VT: 32768 (16KB). P: 49152 + wid*2048 (P1,P2 1KB each)
  const int tid = threadIdx.x;
  const int wid = tid >> 6, lane = tid & 63;
  const int l15 = lane & 15, lhi = lane >> 4;
  char* vtl = lds + 32768;
  char* p1l = lds + 49152 + wid * 2048;
  char* p2l = p1l + 1024;
  const int qt = 31 - blockIdx.y;
  const int bh = blockIdx.x;
  const int b = bh >> 3, h = bh & 7;
  const int qr0 = qt * 64 + wid * 16;
  const float lam = lamp[0];

  // Q fragments in registers (both halves), k-index = (lane>>4)*8+j
  const bf16* qrow = qb + (size_t)(b * 2048 + qr0 + l15) * 2048 + h * 256 + lhi * 8;
  bf16x8 q1f[4], q2f[4];
#pragma unroll
  for (int s = 0; s < 4; ++s) {
    q1f[s] = *(const bf16x8*)(qrow + s * 32);
    q2f[s] = *(const bf16x8*)(qrow + 128 + s * 32);
  }

  const f32x4 fz = {0.f, 0.f, 0.f, 0.f};
  f32x4 y1[16], y2[16];
#pragma unroll
  for (int f = 0; f < 16; ++f) { y1[f] = fz; y2[f] = fz; }
  float l1[4] = {0.f, 0.f, 0.f, 0.f}, l2[4] = {0.f, 0.f, 0.f, 0.f};

  const int nkt = 2 * qt + 2;
  const bf16* kbase = kb + (size_t)(b * 2048) * 2048 + h * 256;
  const bf16* vbase = vtb + (size_t)b * 2048 * 2048 + (size_t)(h * 256) * 2048;

  // staging helpers: chunk (tgroup*4 + kstep) at 1KB granularity, lane = (row l15, kchunk lhi)
  auto stageK = [&](int kt2, int p) {
    const int t0 = kt2 * 32;
    char* kd = lds + p * 16384 + wid * 1024;
    const bf16* sp = kbase + (size_t)(t0 + l15) * 2048 + wid * 32 + lhi * 8;
    gload16(sp, kd);                          // K1 tgroup0
    gload16(sp + 16 * 2048, kd + 4096);       // K1 tgroup1
    gload16(sp + 128, kd + 8192);             // K2 tgroup0
    gload16(sp + 16 * 2048 + 128, kd + 12288);// K2 tgroup1
  };
  auto stageVT = [&](int kt2) {
    const int t0 = kt2 * 32;
    const bf16* vp = vbase + (size_t)(wid * 16 + l15) * 2048 + t0 + lhi * 8;
#pragma unroll
    for (int i = 0; i < 4; ++i)
      gload16(vp + (size_t)i * 64 * 2048, vtl + (i * 4 + wid) * 1024);
  };

  stageK(0, 0);
  stageVT(0);
  __syncthreads();

  for (int kt = 0; kt < nkt; ++kt) {
    const int cur = kt & 1;
    const int t0 = kt * 32;
    const bool active = (t0 <= qr0 + 15);
    if (active) {
      const char* kc = lds + cur * 16384;
      f32x4 s1g[2], s2g[2];
#pragma unroll
      for (int g = 0; g < 2; ++g) {
        f32x4 a1 = fz, a2 = fz;
#pragma unroll
        for (int s = 0; s < 4; ++s) {
          a1 = mfma16x16(q1f[s], *(const bf16x8*)(kc + ((g * 4 + s) * 64 + lane) * 16), a1);
          a2 = mfma16x16(q2f[s], *(const bf16x8*)(kc + 8192 + ((g * 4 + s) * 64 + lane) * 16), a2);
        }
        s1g[g] = a1;
        s2g[g] = a2;
      }
      if (t0 + 31 > qr0) {  // diagonal tile: causal mask
#pragma unroll
        for (int g = 0; g < 2; ++g) {
          int col = t0 + g * 16 + l15;
#pragma unroll
          for (int r = 0; r < 4; ++r) {
            int row = qr0 + lhi * 4 + r;
            if (col > row) { s1g[g][r] = -1e30f; s2g[g][r] = -1e30f; }
          }
        }
      }
      // fixed-max softmax: p = exp(s - 12), accumulate l per-lane, write P tiles
#pragma unroll
      for (int g = 0; g < 2; ++g) {
#pragma unroll
        for (int r = 0; r < 4; ++r) {
          float p1 = __expf(s1g[g][r] - 12.0f);
          float p2 = __expf(s2g[g][r] - 12.0f);
          l1[r] += p1;
          l2[r] += p2;
          int off = ((lhi * 4 + r) * 32 + g * 16 + l15) * 2;
          *(bf16*)(p1l + off) = (bf16)p1;
          *(bf16*)(p2l + off) = (bf16)p2;
        }
      }
    }
    __syncthreads();  // VT[kt] drained (issued one phase ago); P visible (same wave anyway)
    if (active) {
      bf16x8 pa1 = *(const bf16x8*)(p1l + (l15 * 32 + lhi * 8) * 2);
      bf16x8 pa2 = *(const bf16x8*)(p2l + (l15 * 32 + lhi * 8) * 2);
#pragma unroll
      for (int f = 0; f < 16; ++f) {
        bf16x8 vf = *(const bf16x8*)(vtl + (f * 64 + lane) * 16);
        y1[f] = mfma16x16(pa1, vf, y1[f]);
        y2[f] = mfma16x16(pa2, vf, y2[f]);
      }
    }
    __syncthreads();  // all waves done reading VT/K[cur]
    if (kt + 1 < nkt) {  // deferred staging: hides under next iter's QK+exp
      stageK(kt + 1, cur ^ 1);
      stageVT(kt + 1);
    }
  }

  // epilogue: reduce l across the 16-lane row groups, then y = y1/l1 - lam*y2/l2
#pragma unroll
  for (int r = 0; r < 4; ++r) {
    float s1 = l1[r], s2 = l2[r];
#pragma unroll
    for (int m = 1; m <= 8; m <<= 1) {
      s1 += __shfl_xor(s1, m, 64);
      s2 += __shfl_xor(s2, m, 64);
    }
    float inv1 = 1.f / s1;
    float inv2 = lam / s2;
    int row = qr0 + lhi * 4 + r;
    bf16* orow = yb + (size_t)(b * 2048 + row) * 2048 + h * 256 + l15;
#pragma unroll
    for (int f = 0; f < 16; ++f) {
      float v = y1[f][r] * inv1 - y2[f][r] * inv2;
      orow[f * 16] = (bf16)v;
    }
  }
}

// ---------------------------------------------------------------------------
extern "C" void kernel_launch(void* const* d_in, const int* in_sizes, int n_in,
                              void* d_out, int out_size, void* d_ws, size_t ws_size,
                              hipStream_t stream) {
  const float* x = (const float*)d_in[0];
  const float* wq = (const float*)d_in[1];
  const float* wk = (const float*)d_in[2];
  const float* wv = (const float*)d_in[3];
  const float* wo = (const float*)d_in[4];
  const float* lq1 = (const float*)d_in[5];
  const float* lk1 = (const float*)d_in[6];
  const float* lq2 = (const float*)d_in[7];
  const float* lk2 = (const float*)d_in[8];
  float* out = (float*)d_out;
  char* ws = (char*)d_ws;

  if (ws_size < 117440516) return;  // need ~112 MB scratch

  bf16* xb = (bf16*)(ws + 0);             // [4096][2048]
  bf16* wqb = (bf16*)(ws + 16777216);     // [2048][2048]
  bf16* wkb = (bf16*)(ws + 25165824);
  bf16* wvb = (bf16*)(ws + 33554432);
  bf16* wob = (bf16*)(ws + 41943040);
  bf16* qbuf = (bf16*)(ws + 50331648);    // [4096][2048]
  bf16* kbuf = (bf16*)(ws + 67108864);    // [4096][2048]
  bf16* vtb = (bf16*)(ws + 83886080);     // [2][2048 d][2048 t]
  bf16* ybuf = (bf16*)(ws + 100663296);   // [4096][2048]
  float* lam = (float*)(ws + 117440512);

  cast_f32_bf16<<<8192, 256, 0, stream>>>(x, xb, 2097152);
  cast_f32_bf16<<<4096, 256, 0, stream>>>(wq, wqb, 1048576);
  cast_f32_bf16<<<4096, 256, 0, stream>>>(wk, wkb, 1048576);
  cast_f32_bf16<<<4096, 256, 0, stream>>>(wv, wvb, 1048576);
  cast_f32_bf16<<<4096, 256, 0, stream>>>(wo, wob, 1048576);
  lambda_kernel<<<1, 256, 0, stream>>>(lq1, lk1, lq2, lk2, lam);

  dim3 gg(16, 32);  // N/128, M/128
  gemm_nt<0><<<gg, 256, 0, stream>>>(xb, wqb, qbuf, 2048, 2048, 1.f);
  gemm_nt<0><<<gg, 256, 0, stream>>>(xb, wkb, kbuf, 2048, 2048, 1.f);
  gemm_nt<1><<<gg, 256, 0, stream>>>(xb, wvb, vtb, 2048, 2048, 1.f);

  rmsnorm128<<<16384, 256, 0, stream>>>(qbuf, 0.08838834764831845f);  // fold 1/sqrt(128)
  rmsnorm128<<<16384, 256, 0, stream>>>(kbuf, 1.0f);

  attn_kernel<<<dim3(16, 32), 256, 0, stream>>>(qbuf, kbuf, vtb, ybuf, lam);

  gemm_nt<2><<<gg, 256, 0, stream>>>(ybuf, wob, out, 2048, 2048, 0.2f);
}

// Round 3
// 431.173 us; speedup vs baseline: 1.7647x; 1.0873x over previous
//
#include <hip/hip_runtime.h>
#include <stdint.h>

// ---------------------------------------------------------------------------
// Differential attention, bf16 MFMA pipeline.
// B=2 T=2048 C=2048 H=8 HD=256 HALF=128
// ---------------------------------------------------------------------------

typedef __bf16 bf16;
typedef bf16 bf16x8 __attribute__((ext_vector_type(8)));
typedef bf16 bf16x4 __attribute__((ext_vector_type(4)));
typedef bf16 bf16x2 __attribute__((ext_vector_type(2)));
typedef float f32x4 __attribute__((ext_vector_type(4)));

typedef void __attribute__((address_space(1)))* gas_t;
typedef void __attribute__((address_space(3)))* las_t;

__device__ __forceinline__ void gload16(const void* g, void* l) {
  __builtin_amdgcn_global_load_lds((gas_t)(uintptr_t)g, (las_t)(uint32_t)(uintptr_t)l, 16, 0, 0);
}

__device__ __forceinline__ f32x4 mfma16x16(bf16x8 a, bf16x8 b, f32x4 c) {
  return __builtin_amdgcn_mfma_f32_16x16x32_bf16(a, b, c, 0, 0, 0);
}

// ---------------- cast fp32 -> bf16, 4 elems/thread ----------------
__global__ __launch_bounds__(256) void cast_f32_bf16(const float* __restrict__ in,
                                                     bf16* __restrict__ out, int n4) {
  int i = blockIdx.x * 256 + threadIdx.x;
  if (i >= n4) return;
  float4 v = ((const float4*)in)[i];
  bf16x4 o;
  o[0] = (bf16)v.x; o[1] = (bf16)v.y; o[2] = (bf16)v.z; o[3] = (bf16)v.w;
  ((bf16x4*)out)[i] = o;
}

// ---------------- lambda scalar ----------------
__global__ void lambda_kernel(const float* __restrict__ lq1, const float* __restrict__ lk1,
                              const float* __restrict__ lq2, const float* __restrict__ lk2,
                              float* __restrict__ out) {
  __shared__ float red[8];
  int tid = threadIdx.x;
  float a = lq1[tid] * lk1[tid];
  float b = lq2[tid] * lk2[tid];
#pragma unroll
  for (int m = 32; m >= 1; m >>= 1) {
    a += __shfl_xor(a, m, 64);
    b += __shfl_xor(b, m, 64);
  }
  if ((tid & 63) == 0) { red[tid >> 6] = a; red[4 + (tid >> 6)] = b; }
  __syncthreads();
  if (tid == 0) {
    float s1 = red[0] + red[1] + red[2] + red[3];
    float s2 = red[4] + red[5] + red[6] + red[7];
    out[0] = expf(s1) - expf(s2) + 0.8f;
  }
}

// ---------------- fused QKV GEMM (z selects Q/K/V) ----------------
// C[M,N] = A[M,K] @ B[N,K]^T, 128x128 tile, BK=32, 4 waves, frag-ordered LDS.
// z=0: Q -> rms-norm epilogue * 1/sqrt(128) -> qbuf
// z=1: K -> rms-norm epilogue -> kbuf
// z=2: V -> transposed write vtb[b][d][t]
__global__ __launch_bounds__(256) void gemm_qkv(const bf16* __restrict__ A,
                                                const bf16* __restrict__ Bq,
                                                const bf16* __restrict__ Bk,
                                                const bf16* __restrict__ Bv,
                                                bf16* __restrict__ Cq, bf16* __restrict__ Ck,
                                                bf16* __restrict__ Cv) {
  __shared__ char lds[16384];
  char* ldsA = lds;
  char* ldsB = lds + 8192;
  const int K = 2048, N = 2048;
  const int z = blockIdx.z;
  const bf16* B = (z == 0) ? Bq : ((z == 1) ? Bk : Bv);
  const int tid = threadIdx.x;
  const int wid = tid >> 6, lane = tid & 63;
  const int l15 = lane & 15, lhi = lane >> 4;
  const int bm = blockIdx.y * 128, bn = blockIdx.x * 128;
  const int wm = (wid >> 1) * 64, wn = (wid & 1) * 64;

  const f32x4 fz = {0.f, 0.f, 0.f, 0.f};
  f32x4 acc[4][4];
#pragma unroll
  for (int m = 0; m < 4; ++m)
#pragma unroll
    for (int n = 0; n < 4; ++n) acc[m][n] = fz;

  const bf16* aSrc0 = A + (size_t)(bm + wid * 16 + l15) * K + lhi * 8;
  const bf16* aSrc1 = A + (size_t)(bm + 64 + wid * 16 + l15) * K + lhi * 8;
  const bf16* bSrc0 = B + (size_t)(bn + wid * 16 + l15) * K + lhi * 8;
  const bf16* bSrc1 = B + (size_t)(bn + 64 + wid * 16 + l15) * K + lhi * 8;
  char* aDst0 = ldsA + wid * 1024;
  char* aDst1 = ldsA + 4096 + wid * 1024;
  char* bDst0 = ldsB + wid * 1024;
  char* bDst1 = ldsB + 4096 + wid * 1024;

  const int gA = wm >> 4;
  const int gB = wn >> 4;

  for (int k0 = 0; k0 < K; k0 += 32) {
    gload16(aSrc0 + k0, aDst0);
    gload16(aSrc1 + k0, aDst1);
    gload16(bSrc0 + k0, bDst0);
    gload16(bSrc1 + k0, bDst1);
    __syncthreads();
    bf16x8 af[4], bfr[4];
#pragma unroll
    for (int m = 0; m < 4; ++m) af[m] = *(const bf16x8*)(ldsA + ((gA + m) * 64 + lane) * 16);
#pragma unroll
    for (int n = 0; n < 4; ++n) bfr[n] = *(const bf16x8*)(ldsB + ((gB + n) * 64 + lane) * 16);
#pragma unroll
    for (int m = 0; m < 4; ++m)
#pragma unroll
      for (int n = 0; n < 4; ++n) acc[m][n] = mfma16x16(af[m], bfr[n], acc[m][n]);
    __syncthreads();
  }

  if (z == 2) {  // V: transposed write vtb[b][d][t]
#pragma unroll
    for (int m = 0; m < 4; ++m)
#pragma unroll
      for (int n = 0; n < 4; ++n)
#pragma unroll
        for (int r = 0; r < 4; ++r) {
          int row = bm + wm + m * 16 + lhi * 4 + r;
          int col = bn + wn + n * 16 + l15;
          int bb = row >> 11, t = row & 2047;
          Cv[(size_t)bb * 2048 * 2048 + (size_t)col * 2048 + t] = (bf16)acc[m][n][r];
        }
    return;
  }

  // Q/K: rms-norm over the block's 128 cols (= one head-half chunk), f32 precision.
  float* ldsf = (float*)lds;  // [2][128] partial ssq; safe: past final loop barrier
  float ssq[4][4];
#pragma unroll
  for (int m = 0; m < 4; ++m)
#pragma unroll
    for (int r = 0; r < 4; ++r) {
      float s = 0.f;
#pragma unroll
      for (int n = 0; n < 4; ++n) { float v = acc[m][n][r]; s += v * v; }
      s += __shfl_xor(s, 1, 64);
      s += __shfl_xor(s, 2, 64);
      s += __shfl_xor(s, 4, 64);
      s += __shfl_xor(s, 8, 64);
      ssq[m][r] = s;
    }
  __syncthreads();
  if (l15 == 0) {
#pragma unroll
    for (int m = 0; m < 4; ++m)
#pragma unroll
      for (int r = 0; r < 4; ++r)
        ldsf[(wid & 1) * 128 + wm + m * 16 + lhi * 4 + r] = ssq[m][r];
  }
  __syncthreads();
  const float outscale = (z == 0) ? 0.08838834764831845f : 1.0f;  // fold 1/sqrt(128) into q
  bf16* C = (z == 0) ? Cq : Ck;
#pragma unroll
  for (int m = 0; m < 4; ++m) {
#pragma unroll
    for (int r = 0; r < 4; ++r) {
      int rl = wm + m * 16 + lhi * 4 + r;
      float tot = ldsf[rl] + ldsf[128 + rl];
      float sc = rsqrtf(tot * (1.0f / 128.0f) + 1.1920929e-07f) * outscale;
      int row = bm + rl;
#pragma unroll
      for (int n = 0; n < 4; ++n) {
        int col = bn + wn + n * 16 + l15;
        C[(size_t)row * N + col] = (bf16)(acc[m][n][r] * sc);
      }
    }
  }
}

// ---------------- output GEMM: f32 out = (ybuf @ wo^T) * 0.2 ----------------
__global__ __launch_bounds__(256) void gemm_out(const bf16* __restrict__ A, const bf16* __restrict__ B,
                                                float* __restrict__ Cp, int N, int K, float scale) {
  __shared__ char lds[16384];
  char* ldsA = lds;
  char* ldsB = lds + 8192;
  const int tid = threadIdx.x;
  const int wid = tid >> 6, lane = tid & 63;
  const int l15 = lane & 15, lhi = lane >> 4;
  const int bm = blockIdx.y * 128, bn = blockIdx.x * 128;
  const int wm = (wid >> 1) * 64, wn = (wid & 1) * 64;

  const f32x4 fz = {0.f, 0.f, 0.f, 0.f};
  f32x4 acc[4][4];
#pragma unroll
  for (int m = 0; m < 4; ++m)
#pragma unroll
    for (int n = 0; n < 4; ++n) acc[m][n] = fz;

  const bf16* aSrc0 = A + (size_t)(bm + wid * 16 + l15) * K + lhi * 8;
  const bf16* aSrc1 = A + (size_t)(bm + 64 + wid * 16 + l15) * K + lhi * 8;
  const bf16* bSrc0 = B + (size_t)(bn + wid * 16 + l15) * K + lhi * 8;
  const bf16* bSrc1 = B + (size_t)(bn + 64 + wid * 16 + l15) * K + lhi * 8;
  char* aDst0 = ldsA + wid * 1024;
  char* aDst1 = ldsA + 4096 + wid * 1024;
  char* bDst0 = ldsB + wid * 1024;
  char* bDst1 = ldsB + 4096 + wid * 1024;

  const int gA = wm >> 4;
  const int gB = wn >> 4;

  for (int k0 = 0; k0 < K; k0 += 32) {
    gload16(aSrc0 + k0, aDst0);
    gload16(aSrc1 + k0, aDst1);
    gload16(bSrc0 + k0, bDst0);
    gload16(bSrc1 + k0, bDst1);
    __syncthreads();
    bf16x8 af[4], bfr[4];
#pragma unroll
    for (int m = 0; m < 4; ++m) af[m] = *(const bf16x8*)(ldsA + ((gA + m) * 64 + lane) * 16);
#pragma unroll
    for (int n = 0; n < 4; ++n) bfr[n] = *(const bf16x8*)(ldsB + ((gB + n) * 64 + lane) * 16);
#pragma unroll
    for (int m = 0; m < 4; ++m)
#pragma unroll
      for (int n = 0; n < 4; ++n) acc[m][n] = mfma16x16(af[m], bfr[n], acc[m][n]);
    __syncthreads();
  }

#pragma unroll
  for (int m = 0; m < 4; ++m)
#pragma unroll
    for (int n = 0; n < 4; ++n)
#pragma unroll
      for (int r = 0; r < 4; ++r) {
        int row = bm + wm + m * 16 + lhi * 4 + r;
        int col = bn + wn + n * 16 + l15;
        Cp[(size_t)row * N + col] = acc[m][n][r] * scale;
      }
}

// ---------------- dual-stream causal flash attention, v3 ----------------
// Fixed-max softmax (scores bounded: q,k rms-normed, q carries 1/sqrt(128)).
// Shared per-wave P buffer across streams (in-wave DS ordering) -> LDS 52KB
// -> 3 blocks/CU. K double-buffered; staging deferred past barrier2.
__global__ __launch_bounds__(256) void attn_kernel(const bf16* __restrict__ qb, const bf16* __restrict__ kb,
                                                   const bf16* __restrict__ vtb, bf16* __restrict__ yb,
                                                   const float* __restrict__ lamp) {
  __shared__ char lds[53248];
  // K ping p: lds + p*16384 (K1 8KB, K2 8KB). VT: 32768 (16KB). P: 49152 + wid*1024
  const int tid = threadIdx.x;
  const int wid = tid >> 6, lane = tid & 63;
  const int l15 = lane & 15, lhi = lane >> 4;
  char* vtl = lds + 32768;
  char* pbf = lds + 49152 + wid * 1024;
  const int qt = 31 - blockIdx.y;
  const int bh = blockIdx.x;
  const int b = bh >> 3, h = bh & 7;
  const int qr0 = qt * 64 + wid * 16;
  const float lam = lamp[0];

  const bf16* qrow = qb + (size_t)(b * 2048 + qr0 + l15) * 2048 + h * 256 + lhi * 8;
  bf16x8 q1f[4], q2f[4];
#pragma unroll
  for (int s = 0; s < 4; ++s) {
    q1f[s] = *(const bf16x8*)(qrow + s * 32);
    q2f[s] = *(const bf16x8*)(qrow + 128 + s * 32);
  }

  const f32x4 fz = {0.f, 0.f, 0.f, 0.f};
  f32x4 y1[16], y2[16];
#pragma unroll
  for (int f = 0; f < 16; ++f) { y1[f] = fz; y2[f] = fz; }
  float l1[4] = {0.f, 0.f, 0.f, 0.f}, l2[4] = {0.f, 0.f, 0.f, 0.f};

  const int nkt = 2 * qt + 2;
  const bf16* kbase = kb + (size_t)(b * 2048) * 2048 + h * 256;
  const bf16* vbase = vtb + (size_t)b * 2048 * 2048 + (size_t)(h * 256) * 2048;

  auto stageK = [&](int kt2, int p) {
    const int t0 = kt2 * 32;
    char* kd = lds + p * 16384 + wid * 1024;
    const bf16* sp = kbase + (size_t)(t0 + l15) * 2048 + wid * 32 + lhi * 8;
    gload16(sp, kd);
    gload16(sp + 16 * 2048, kd + 4096);
    gload16(sp + 128, kd + 8192);
    gload16(sp + 16 * 2048 + 128, kd + 12288);
  };
  auto stageVT = [&](int kt2) {
    const int t0 = kt2 * 32;
    const bf16* vp = vbase + (size_t)(wid * 16 + l15) * 2048 + t0 + lhi * 8;
#pragma unroll
    for (int i = 0; i < 4; ++i)
      gload16(vp + (size_t)i * 64 * 2048, vtl + (i * 4 + wid) * 1024);
  };

  stageK(0, 0);
  stageVT(0);
  __syncthreads();

  for (int kt = 0; kt < nkt; ++kt) {
    const int cur = kt & 1;
    const int t0 = kt * 32;
    const bool active = (t0 <= qr0 + 15);
    f32x4 s1g[2], s2g[2];
    if (active) {
      const char* kc = lds + cur * 16384;
#pragma unroll
      for (int g = 0; g < 2; ++g) {
        f32x4 a1 = fz, a2 = fz;
#pragma unroll
        for (int s = 0; s < 4; ++s) {
          a1 = mfma16x16(q1f[s], *(const bf16x8*)(kc + ((g * 4 + s) * 64 + lane) * 16), a1);
          a2 = mfma16x16(q2f[s], *(const bf16x8*)(kc + 8192 + ((g * 4 + s) * 64 + lane) * 16), a2);
        }
        s1g[g] = a1;
        s2g[g] = a2;
      }
      if (t0 + 31 > qr0) {
#pragma unroll
        for (int g = 0; g < 2; ++g) {
          int col = t0 + g * 16 + l15;
#pragma unroll
          for (int r = 0; r < 4; ++r) {
            int row = qr0 + lhi * 4 + r;
            if (col > row) { s1g[g][r] = -1e30f; s2g[g][r] = -1e30f; }
          }
        }
      }
      // exp both streams; write P1; keep P2 in regs
#pragma unroll
      for (int g = 0; g < 2; ++g) {
#pragma unroll
        for (int r = 0; r < 4; ++r) {
          float p1 = __expf(s1g[g][r] - 12.0f);
          float p2 = __expf(s2g[g][r] - 12.0f);
          l1[r] += p1;
          l2[r] += p2;
          *(bf16*)(pbf + ((lhi * 4 + r) * 32 + g * 16 + l15) * 2) = (bf16)p1;
          s2g[g][r] = p2;
        }
      }
    }
    __syncthreads();  // VT[kt] drained
    if (active) {
      bf16x8 pa1 = *(const bf16x8*)(pbf + (l15 * 32 + lhi * 8) * 2);
#pragma unroll
      for (int f = 0; f < 16; ++f)
        y1[f] = mfma16x16(pa1, *(const bf16x8*)(vtl + (f * 64 + lane) * 16), y1[f]);
      // overwrite P buffer with stream 2 (same-wave DS ordering: pa1 read precedes)
#pragma unroll
      for (int g = 0; g < 2; ++g)
#pragma unroll
        for (int r = 0; r < 4; ++r)
          *(bf16*)(pbf + ((lhi * 4 + r) * 32 + g * 16 + l15) * 2) = (bf16)s2g[g][r];
      bf16x8 pa2 = *(const bf16x8*)(pbf + (l15 * 32 + lhi * 8) * 2);
#pragma unroll
      for (int f = 0; f < 16; ++f)
        y2[f] = mfma16x16(pa2, *(const bf16x8*)(vtl + (f * 64 + lane) * 16), y2[f]);
    }
    __syncthreads();
    if (kt + 1 < nkt) {
      stageK(kt + 1, cur ^ 1);
      stageVT(kt + 1);
    }
  }

#pragma unroll
  for (int r = 0; r < 4; ++r) {
    float s1 = l1[r], s2 = l2[r];
#pragma unroll
    for (int m = 1; m <= 8; m <<= 1) {
      s1 += __shfl_xor(s1, m, 64);
      s2 += __shfl_xor(s2, m, 64);
    }
    float inv1 = 1.f / s1;
    float inv2 = lam / s2;
    int row = qr0 + lhi * 4 + r;
    bf16* orow = yb + (size_t)(b * 2048 + row) * 2048 + h * 256 + l15;
#pragma unroll
    for (int f = 0; f < 16; ++f) {
      float v = y1[f][r] * inv1 - y2[f][r] * inv2;
      orow[f * 16] = (bf16)v;
    }
  }
}

// ---------------------------------------------------------------------------
extern "C" void kernel_launch(void* const* d_in, const int* in_sizes, int n_in,
                              void* d_out, int out_size, void* d_ws, size_t ws_size,
                              hipStream_t stream) {
  const float* x = (const float*)d_in[0];
  const float* wq = (const float*)d_in[1];
  const float* wk = (const float*)d_in[2];
  const float* wv = (const float*)d_in[3];
  const float* wo = (const float*)d_in[4];
  const float* lq1 = (const float*)d_in[5];
  const float* lk1 = (const float*)d_in[6];
  const float* lq2 = (const float*)d_in[7];
  const float* lk2 = (const float*)d_in[8];
  float* out = (float*)d_out;
  char* ws = (char*)d_ws;

  if (ws_size < 117440516) return;

  bf16* xb = (bf16*)(ws + 0);             // [4096][2048]
  bf16* wqb = (bf16*)(ws + 16777216);     // [2048][2048]
  bf16* wkb = (bf16*)(ws + 25165824);
  bf16* wvb = (bf16*)(ws + 33554432);
  bf16* wob = (bf16*)(ws + 41943040);
  bf16* qbuf = (bf16*)(ws + 50331648);    // [4096][2048]
  bf16* kbuf = (bf16*)(ws + 67108864);    // [4096][2048]
  bf16* vtb = (bf16*)(ws + 83886080);     // [2][2048 d][2048 t]
  bf16* ybuf = (bf16*)(ws + 100663296);   // [4096][2048]
  float* lam = (float*)(ws + 117440512);

  cast_f32_bf16<<<8192, 256, 0, stream>>>(x, xb, 2097152);
  cast_f32_bf16<<<4096, 256, 0, stream>>>(wq, wqb, 1048576);
  cast_f32_bf16<<<4096, 256, 0, stream>>>(wk, wkb, 1048576);
  cast_f32_bf16<<<4096, 256, 0, stream>>>(wv, wvb, 1048576);
  cast_f32_bf16<<<4096, 256, 0, stream>>>(wo, wob, 1048576);
  lambda_kernel<<<1, 256, 0, stream>>>(lq1, lk1, lq2, lk2, lam);

  gemm_qkv<<<dim3(16, 32, 3), 256, 0, stream>>>(xb, wqb, wkb, wvb, qbuf, kbuf, vtb);

  attn_kernel<<<dim3(16, 32), 256, 0, stream>>>(qbuf, kbuf, vtb, ybuf, lam);

  gemm_out<<<dim3(16, 32), 256, 0, stream>>>(ybuf, wob, out, 2048, 2048, 0.2f);
}

// Round 4
// 375.922 us; speedup vs baseline: 2.0240x; 1.1470x over previous
//
#include <hip/hip_runtime.h>
#include <stdint.h>

// ---------------------------------------------------------------------------
// Differential attention, bf16 MFMA pipeline.
// B=2 T=2048 C=2048 H=8 HD=256 HALF=128
// ---------------------------------------------------------------------------

typedef __bf16 bf16;
typedef bf16 bf16x8 __attribute__((ext_vector_type(8)));
typedef bf16 bf16x4 __attribute__((ext_vector_type(4)));
typedef bf16 bf16x2 __attribute__((ext_vector_type(2)));
typedef float f32x4 __attribute__((ext_vector_type(4)));

typedef void __attribute__((address_space(1)))* gas_t;
typedef void __attribute__((address_space(3)))* las_t;

__device__ __forceinline__ void gload16(const void* g, void* l) {
  __builtin_amdgcn_global_load_lds((gas_t)(uintptr_t)g, (las_t)(uint32_t)(uintptr_t)l, 16, 0, 0);
}

__device__ __forceinline__ f32x4 mfma16x16(bf16x8 a, bf16x8 b, f32x4 c) {
  return __builtin_amdgcn_mfma_f32_16x16x32_bf16(a, b, c, 0, 0, 0);
}

// barrier with scheduling fences on both sides: nothing crosses.
#define FENCE_BAR()                         \
  do {                                      \
    __builtin_amdgcn_sched_barrier(0);      \
    __builtin_amdgcn_s_barrier();           \
    __builtin_amdgcn_sched_barrier(0);      \
  } while (0)

// ---------------- cast fp32 -> bf16, 4 elems/thread ----------------
__global__ __launch_bounds__(256) void cast_f32_bf16(const float* __restrict__ in,
                                                     bf16* __restrict__ out, int n4) {
  int i = blockIdx.x * 256 + threadIdx.x;
  if (i >= n4) return;
  float4 v = ((const float4*)in)[i];
  bf16x4 o;
  o[0] = (bf16)v.x; o[1] = (bf16)v.y; o[2] = (bf16)v.z; o[3] = (bf16)v.w;
  ((bf16x4*)out)[i] = o;
}

// ---------------- lambda scalar ----------------
__global__ void lambda_kernel(const float* __restrict__ lq1, const float* __restrict__ lk1,
                              const float* __restrict__ lq2, const float* __restrict__ lk2,
                              float* __restrict__ out) {
  __shared__ float red[8];
  int tid = threadIdx.x;
  float a = lq1[tid] * lk1[tid];
  float b = lq2[tid] * lk2[tid];
#pragma unroll
  for (int m = 32; m >= 1; m >>= 1) {
    a += __shfl_xor(a, m, 64);
    b += __shfl_xor(b, m, 64);
  }
  if ((tid & 63) == 0) { red[tid >> 6] = a; red[4 + (tid >> 6)] = b; }
  __syncthreads();
  if (tid == 0) {
    float s1 = red[0] + red[1] + red[2] + red[3];
    float s2 = red[4] + red[5] + red[6] + red[7];
    out[0] = expf(s1) - expf(s2) + 0.8f;
  }
}

// ---------------- fused QKV GEMM, 256x256 tile, 8-phase pipelined ----------------
// C = A[4096,2048] @ B[2048,2048]^T per z. 8 waves (2M x 4N), BK=64, LDS 128KB
// (2 K-tile buffers of A 32KB + B 32KB, fragment-ordered -> conflict-free).
// Schedule per K-tile t (4 phases (ks,nh), 16 MFMA each):
//   P00: read A[ks0](8)+B[ks0]n01(2); stage B1(t+1)->buf[t+1]; bar; MFMA; bar
//   P01: read B[ks0]n23(2);           stage A0(t+2)->buf[t];   bar; MFMA; bar
//   P10: read A[ks1](8)+B[ks1]n01(2); stage B0(t+2)->buf[t];   bar; MFMA; bar
//   P11: read B[ks1]n23(2);           stage A1(t+2)->buf[t];   bar; MFMA; vmcnt(6); bar
// Invariant: every stage targets a region whose reads completed in an earlier
// phase (block-wide via that phase's trailing barrier). vmcnt(6) leaves exactly
// the 3 newest half-tiles (t+2's A0,B0,A1) in flight; everything older landed,
// so tile t+1 is resident when its P00 reads begin.
__global__ __launch_bounds__(512, 2) void gemm_qkv8(const bf16* __restrict__ A,
                                                    const bf16* __restrict__ Bq,
                                                    const bf16* __restrict__ Bk,
                                                    const bf16* __restrict__ Bv,
                                                    bf16* __restrict__ Cq, bf16* __restrict__ Ck,
                                                    bf16* __restrict__ Cv) {
  __shared__ char lds[131072];
  const int K = 2048, N = 2048, nt = 32;

  // XCD-bijective swizzle over 384 blocks (384 % 8 == 0)
  int p = (blockIdx.z * gridDim.y + blockIdx.y) * gridDim.x + blockIdx.x;
  const int nwg = 384, cpx = nwg >> 3;
  int lid = (p & 7) * cpx + (p >> 3);
  int z = lid >> 7;           // / 128 tiles per z
  int rem = lid & 127;
  int bym = rem >> 3;         // M tile (16)
  int bxn = rem & 7;          // N tile (8)
  const bf16* Bz = (z == 0) ? Bq : ((z == 1) ? Bk : Bv);
  const int bm = bym * 256, bn = bxn * 256;

  const int tid = threadIdx.x;
  const int wid = tid >> 6, lane = tid & 63;
  const int l15 = lane & 15, lhi = lane >> 4;
  const int wm = wid >> 2, wn = wid & 3;

  // staging source pointers (fragment-ordered: lane l -> row (l&15), kchunk (l>>4)*8)
  const bf16* aS0 = A + (size_t)(bm + wid * 16 + l15) * K + lhi * 8;
  const bf16* bS0 = Bz + (size_t)(bn + wid * 16 + l15) * K + lhi * 8;
  // LDS: buf p at p*65536; A half ks at +ks*16384, frag mf at +mf*1024.
  //      B at +32768 same layout.
  auto stA = [&](int t, int ks, int pb) {
    char* d = lds + pb * 65536 + ks * 16384 + wid * 1024;
    const bf16* s = aS0 + t * 64 + ks * 32;
    gload16(s, d);
    gload16(s + (size_t)128 * K, d + 8192);
  };
  auto stB = [&](int t, int ks, int pb) {
    char* d = lds + pb * 65536 + 32768 + ks * 16384 + wid * 1024;
    const bf16* s = bS0 + t * 64 + ks * 32;
    gload16(s, d);
    gload16(s + (size_t)128 * K, d + 8192);
  };

  const f32x4 fz = {0.f, 0.f, 0.f, 0.f};
  f32x4 acc[8][4];
#pragma unroll
  for (int m = 0; m < 8; ++m)
#pragma unroll
    for (int n = 0; n < 4; ++n) acc[m][n] = fz;

  // prologue: tile0 (A0,B0,A1,B1) + tile1 (A0,B0,A1); B1(1) staged at t=0 P00.
  stA(0, 0, 0); stB(0, 0, 0); stA(0, 1, 0); stB(0, 1, 0);
  stA(1, 0, 1); stB(1, 0, 1); stA(1, 1, 1);
  asm volatile("s_waitcnt vmcnt(6)" ::: "memory");
  FENCE_BAR();

  for (int t = 0; t < nt; ++t) {
    const int cur = t & 1;
    const char* cA = lds + cur * 65536;
    const char* cB = cA + 32768;
    bf16x8 a[8], b0, b1, b2, b3;

    // ---- P00: ks0, n01 ----
#pragma unroll
    for (int m = 0; m < 8; ++m) a[m] = *(const bf16x8*)(cA + (wm * 8 + m) * 1024 + lane * 16);
    b0 = *(const bf16x8*)(cB + (wn * 4 + 0) * 1024 + lane * 16);
    b1 = *(const bf16x8*)(cB + (wn * 4 + 1) * 1024 + lane * 16);
    if (t + 1 < nt) stB(t + 1, 1, cur ^ 1);
    FENCE_BAR();
    __builtin_amdgcn_s_setprio(1);
#pragma unroll
    for (int m = 0; m < 8; ++m) {
      acc[m][0] = mfma16x16(a[m], b0, acc[m][0]);
      acc[m][1] = mfma16x16(a[m], b1, acc[m][1]);
    }
    __builtin_amdgcn_s_setprio(0);
    FENCE_BAR();

    // ---- P01: ks0, n23 ----
    b2 = *(const bf16x8*)(cB + (wn * 4 + 2) * 1024 + lane * 16);
    b3 = *(const bf16x8*)(cB + (wn * 4 + 3) * 1024 + lane * 16);
    if (t + 2 < nt) stA(t + 2, 0, cur);
    FENCE_BAR();
    __builtin_amdgcn_s_setprio(1);
#pragma unroll
    for (int m = 0; m < 8; ++m) {
      acc[m][2] = mfma16x16(a[m], b2, acc[m][2]);
      acc[m][3] = mfma16x16(a[m], b3, acc[m][3]);
    }
    __builtin_amdgcn_s_setprio(0);
    FENCE_BAR();

    // ---- P10: ks1, n01 ----
#pragma unroll
    for (int m = 0; m < 8; ++m)
      a[m] = *(const bf16x8*)(cA + 16384 + (wm * 8 + m) * 1024 + lane * 16);
    b0 = *(const bf16x8*)(cB + 16384 + (wn * 4 + 0) * 1024 + lane * 16);
    b1 = *(const bf16x8*)(cB + 16384 + (wn * 4 + 1) * 1024 + lane * 16);
    if (t + 2 < nt) stB(t + 2, 0, cur);
    FENCE_BAR();
    __builtin_amdgcn_s_setprio(1);
#pragma unroll
    for (int m = 0; m < 8; ++m) {
      acc[m][0] = mfma16x16(a[m], b0, acc[m][0]);
      acc[m][1] = mfma16x16(a[m], b1, acc[m][1]);
    }
    __builtin_amdgcn_s_setprio(0);
    FENCE_BAR();

    // ---- P11: ks1, n23 ----
    b2 = *(const bf16x8*)(cB + 16384 + (wn * 4 + 2) * 1024 + lane * 16);
    b3 = *(const bf16x8*)(cB + 16384 + (wn * 4 + 3) * 1024 + lane * 16);
    if (t + 2 < nt) stA(t + 2, 1, cur);
    FENCE_BAR();
    __builtin_amdgcn_s_setprio(1);
#pragma unroll
    for (int m = 0; m < 8; ++m) {
      acc[m][2] = mfma16x16(a[m], b2, acc[m][2]);
      acc[m][3] = mfma16x16(a[m], b3, acc[m][3]);
    }
    __builtin_amdgcn_s_setprio(0);
    if (t < nt - 2) {
      asm volatile("s_waitcnt vmcnt(6)" ::: "memory");
    } else {
      asm volatile("s_waitcnt vmcnt(0)" ::: "memory");
    }
    FENCE_BAR();
  }

  // ---- epilogue ----
  if (z == 2) {  // V: transposed write vtb[b][d][t]
#pragma unroll
    for (int m = 0; m < 8; ++m)
#pragma unroll
      for (int n = 0; n < 4; ++n)
#pragma unroll
        for (int r = 0; r < 4; ++r) {
          int row = bm + wm * 128 + m * 16 + lhi * 4 + r;
          int col = bn + wn * 64 + n * 16 + l15;
          int bb = row >> 11, tt = row & 2047;
          Cv[(size_t)bb * 2048 * 2048 + (size_t)col * 2048 + tt] = (bf16)acc[m][n][r];
        }
    return;
  }
  // Q/K: rms-norm over 128-col chunks (two chunks per block; wave covers half a chunk)
  float* ldsf = (float*)lds;  // [256 rows][4 wn] partials; buffers dead after final barrier
#pragma unroll
  for (int m = 0; m < 8; ++m)
#pragma unroll
    for (int r = 0; r < 4; ++r) {
      float s = acc[m][0][r] * acc[m][0][r] + acc[m][1][r] * acc[m][1][r] +
                acc[m][2][r] * acc[m][2][r] + acc[m][3][r] * acc[m][3][r];
      s += __shfl_xor(s, 1, 64);
      s += __shfl_xor(s, 2, 64);
      s += __shfl_xor(s, 4, 64);
      s += __shfl_xor(s, 8, 64);
      if (l15 == 0) ldsf[(wm * 128 + m * 16 + lhi * 4 + r) * 4 + wn] = s;
    }
  __syncthreads();
  const float osc = (z == 0) ? 0.08838834764831845f : 1.0f;  // fold 1/sqrt(128) into q
  bf16* C = (z == 0) ? Cq : Ck;
#pragma unroll
  for (int m = 0; m < 8; ++m) {
#pragma unroll
    for (int r = 0; r < 4; ++r) {
      int rl = wm * 128 + m * 16 + lhi * 4 + r;
      float tot = ldsf[rl * 4 + (wn & 2)] + ldsf[rl * 4 + (wn & 2) + 1];
      float sc = rsqrtf(tot * (1.0f / 128.0f) + 1.1920929e-07f) * osc;
#pragma unroll
      for (int n = 0; n < 4; ++n) {
        int col = bn + wn * 64 + n * 16 + l15;
        C[(size_t)(bm + rl) * N + col] = (bf16)(acc[m][n][r] * sc);
      }
    }
  }
}

// ---------------- output GEMM: f32 out = (ybuf @ wo^T) * 0.2 ----------------
__global__ __launch_bounds__(256) void gemm_out(const bf16* __restrict__ A, const bf16* __restrict__ B,
                                                float* __restrict__ Cp, int N, int K, float scale) {
  __shared__ char lds[16384];
  char* ldsA = lds;
  char* ldsB = lds + 8192;
  const int tid = threadIdx.x;
  const int wid = tid >> 6, lane = tid & 63;
  const int l15 = lane & 15, lhi = lane >> 4;
  const int bm = blockIdx.y * 128, bn = blockIdx.x * 128;
  const int wm = (wid >> 1) * 64, wn = (wid & 1) * 64;

  const f32x4 fz = {0.f, 0.f, 0.f, 0.f};
  f32x4 acc[4][4];
#pragma unroll
  for (int m = 0; m < 4; ++m)
#pragma unroll
    for (int n = 0; n < 4; ++n) acc[m][n] = fz;

  const bf16* aSrc0 = A + (size_t)(bm + wid * 16 + l15) * K + lhi * 8;
  const bf16* aSrc1 = A + (size_t)(bm + 64 + wid * 16 + l15) * K + lhi * 8;
  const bf16* bSrc0 = B + (size_t)(bn + wid * 16 + l15) * K + lhi * 8;
  const bf16* bSrc1 = B + (size_t)(bn + 64 + wid * 16 + l15) * K + lhi * 8;
  char* aDst0 = ldsA + wid * 1024;
  char* aDst1 = ldsA + 4096 + wid * 1024;
  char* bDst0 = ldsB + wid * 1024;
  char* bDst1 = ldsB + 4096 + wid * 1024;

  const int gA = wm >> 4;
  const int gB = wn >> 4;

  for (int k0 = 0; k0 < K; k0 += 32) {
    gload16(aSrc0 + k0, aDst0);
    gload16(aSrc1 + k0, aDst1);
    gload16(bSrc0 + k0, bDst0);
    gload16(bSrc1 + k0, bDst1);
    __syncthreads();
    bf16x8 af[4], bfr[4];
#pragma unroll
    for (int m = 0; m < 4; ++m) af[m] = *(const bf16x8*)(ldsA + ((gA + m) * 64 + lane) * 16);
#pragma unroll
    for (int n = 0; n < 4; ++n) bfr[n] = *(const bf16x8*)(ldsB + ((gB + n) * 64 + lane) * 16);
#pragma unroll
    for (int m = 0; m < 4; ++m)
#pragma unroll
      for (int n = 0; n < 4; ++n) acc[m][n] = mfma16x16(af[m], bfr[n], acc[m][n]);
    __syncthreads();
  }

#pragma unroll
  for (int m = 0; m < 4; ++m)
#pragma unroll
    for (int n = 0; n < 4; ++n)
#pragma unroll
      for (int r = 0; r < 4; ++r) {
        int row = bm + wm + m * 16 + lhi * 4 + r;
        int col = bn + wn + n * 16 + l15;
        Cp[(size_t)row * N + col] = acc[m][n][r] * scale;
      }
}

// ---------------- dual-stream causal flash attention (round-3 v3) ----------------
__global__ __launch_bounds__(256) void attn_kernel(const bf16* __restrict__ qb, const bf16* __restrict__ kb,
                                                   const bf16* __restrict__ vtb, bf16* __restrict__ yb,
                                                   const float* __restrict__ lamp) {
  __shared__ char lds[53248];
  const int tid = threadIdx.x;
  const int wid = tid >> 6, lane = tid & 63;
  const int l15 = lane & 15, lhi = lane >> 4;
  char* vtl = lds + 32768;
  char* pbf = lds + 49152 + wid * 1024;
  const int qt = 31 - blockIdx.y;
  const int bh = blockIdx.x;
  const int b = bh >> 3, h = bh & 7;
  const int qr0 = qt * 64 + wid * 16;
  const float lam = lamp[0];

  const bf16* qrow = qb + (size_t)(b * 2048 + qr0 + l15) * 2048 + h * 256 + lhi * 8;
  bf16x8 q1f[4], q2f[4];
#pragma unroll
  for (int s = 0; s < 4; ++s) {
    q1f[s] = *(const bf16x8*)(qrow + s * 32);
    q2f[s] = *(const bf16x8*)(qrow + 128 + s * 32);
  }

  const f32x4 fz = {0.f, 0.f, 0.f, 0.f};
  f32x4 y1[16], y2[16];
#pragma unroll
  for (int f = 0; f < 16; ++f) { y1[f] = fz; y2[f] = fz; }
  float l1[4] = {0.f, 0.f, 0.f, 0.f}, l2[4] = {0.f, 0.f, 0.f, 0.f};

  const int nkt = 2 * qt + 2;
  const bf16* kbase = kb + (size_t)(b * 2048) * 2048 + h * 256;
  const bf16* vbase = vtb + (size_t)b * 2048 * 2048 + (size_t)(h * 256) * 2048;

  auto stageK = [&](int kt2, int p) {
    const int t0 = kt2 * 32;
    char* kd = lds + p * 16384 + wid * 1024;
    const bf16* sp = kbase + (size_t)(t0 + l15) * 2048 + wid * 32 + lhi * 8;
    gload16(sp, kd);
    gload16(sp + 16 * 2048, kd + 4096);
    gload16(sp + 128, kd + 8192);
    gload16(sp + 16 * 2048 + 128, kd + 12288);
  };
  auto stageVT = [&](int kt2) {
    const int t0 = kt2 * 32;
    const bf16* vp = vbase + (size_t)(wid * 16 + l15) * 2048 + t0 + lhi * 8;
#pragma unroll
    for (int i = 0; i < 4; ++i)
      gload16(vp + (size_t)i * 64 * 2048, vtl + (i * 4 + wid) * 1024);
  };

  stageK(0, 0);
  stageVT(0);
  __syncthreads();

  for (int kt = 0; kt < nkt; ++kt) {
    const int cur = kt & 1;
    const int t0 = kt * 32;
    const bool active = (t0 <= qr0 + 15);
    f32x4 s1g[2], s2g[2];
    if (active) {
      const char* kc = lds + cur * 16384;
#pragma unroll
      for (int g = 0; g < 2; ++g) {
        f32x4 a1 = fz, a2 = fz;
#pragma unroll
        for (int s = 0; s < 4; ++s) {
          a1 = mfma16x16(q1f[s], *(const bf16x8*)(kc + ((g * 4 + s) * 64 + lane) * 16), a1);
          a2 = mfma16x16(q2f[s], *(const bf16x8*)(kc + 8192 + ((g * 4 + s) * 64 + lane) * 16), a2);
        }
        s1g[g] = a1;
        s2g[g] = a2;
      }
      if (t0 + 31 > qr0) {
#pragma unroll
        for (int g = 0; g < 2; ++g) {
          int col = t0 + g * 16 + l15;
#pragma unroll
          for (int r = 0; r < 4; ++r) {
            int row = qr0 + lhi * 4 + r;
            if (col > row) { s1g[g][r] = -1e30f; s2g[g][r] = -1e30f; }
          }
        }
      }
#pragma unroll
      for (int g = 0; g < 2; ++g) {
#pragma unroll
        for (int r = 0; r < 4; ++r) {
          float p1 = __expf(s1g[g][r] - 12.0f);
          float p2 = __expf(s2g[g][r] - 12.0f);
          l1[r] += p1;
          l2[r] += p2;
          *(bf16*)(pbf + ((lhi * 4 + r) * 32 + g * 16 + l15) * 2) = (bf16)p1;
          s2g[g][r] = p2;
        }
      }
    }
    __syncthreads();
    if (active) {
      bf16x8 pa1 = *(const bf16x8*)(pbf + (l15 * 32 + lhi * 8) * 2);
#pragma unroll
      for (int f = 0; f < 16; ++f)
        y1[f] = mfma16x16(pa1, *(const bf16x8*)(vtl + (f * 64 + lane) * 16), y1[f]);
#pragma unroll
      for (int g = 0; g < 2; ++g)
#pragma unroll
        for (int r = 0; r < 4; ++r)
          *(bf16*)(pbf + ((lhi * 4 + r) * 32 + g * 16 + l15) * 2) = (bf16)s2g[g][r];
      bf16x8 pa2 = *(const bf16x8*)(pbf + (l15 * 32 + lhi * 8) * 2);
#pragma unroll
      for (int f = 0; f < 16; ++f)
        y2[f] = mfma16x16(pa2, *(const bf16x8*)(vtl + (f * 64 + lane) * 16), y2[f]);
    }
    __syncthreads();
    if (kt + 1 < nkt) {
      stageK(kt + 1, cur ^ 1);
      stageVT(kt + 1);
    }
  }

#pragma unroll
  for (int r = 0; r < 4; ++r) {
    float s1 = l1[r], s2 = l2[r];
#pragma unroll
    for (int m = 1; m <= 8; m <<= 1) {
      s1 += __shfl_xor(s1, m, 64);
      s2 += __shfl_xor(s2, m, 64);
    }
    float inv1 = 1.f / s1;
    float inv2 = lam / s2;
    int row = qr0 + lhi * 4 + r;
    bf16* orow = yb + (size_t)(b * 2048 + row) * 2048 + h * 256 + l15;
#pragma unroll
    for (int f = 0; f < 16; ++f) {
      float v = y1[f][r] * inv1 - y2[f][r] * inv2;
      orow[f * 16] = (bf16)v;
    }
  }
}

// ---------------------------------------------------------------------------
extern "C" void kernel_launch(void* const* d_in, const int* in_sizes, int n_in,
                              void* d_out, int out_size, void* d_ws, size_t ws_size,
                              hipStream_t stream) {
  const float* x = (const float*)d_in[0];
  const float* wq = (const float*)d_in[1];
  const float* wk = (const float*)d_in[2];
  const float* wv = (const float*)d_in[3];
  const float* wo = (const float*)d_in[4];
  const float* lq1 = (const float*)d_in[5];
  const float* lk1 = (const float*)d_in[6];
  const float* lq2 = (const float*)d_in[7];
  const float* lk2 = (const float*)d_in[8];
  float* out = (float*)d_out;
  char* ws = (char*)d_ws;

  if (ws_size < 117440516) return;

  bf16* xb = (bf16*)(ws + 0);             // [4096][2048]
  bf16* wqb = (bf16*)(ws + 16777216);     // [2048][2048]
  bf16* wkb = (bf16*)(ws + 25165824);
  bf16* wvb = (bf16*)(ws + 33554432);
  bf16* wob = (bf16*)(ws + 41943040);
  bf16* qbuf = (bf16*)(ws + 50331648);    // [4096][2048]
  bf16* kbuf = (bf16*)(ws + 67108864);    // [4096][2048]
  bf16* vtb = (bf16*)(ws + 83886080);     // [2][2048 d][2048 t]
  bf16* ybuf = (bf16*)(ws + 100663296);   // [4096][2048]
  float* lam = (float*)(ws + 117440512);

  cast_f32_bf16<<<8192, 256, 0, stream>>>(x, xb, 2097152);
  cast_f32_bf16<<<4096, 256, 0, stream>>>(wq, wqb, 1048576);
  cast_f32_bf16<<<4096, 256, 0, stream>>>(wk, wkb, 1048576);
  cast_f32_bf16<<<4096, 256, 0, stream>>>(wv, wvb, 1048576);
  cast_f32_bf16<<<4096, 256, 0, stream>>>(wo, wob, 1048576);
  lambda_kernel<<<1, 256, 0, stream>>>(lq1, lk1, lq2, lk2, lam);

  gemm_qkv8<<<dim3(8, 16, 3), 512, 0, stream>>>(xb, wqb, wkb, wvb, qbuf, kbuf, vtb);

  attn_kernel<<<dim3(16, 32), 256, 0, stream>>>(qbuf, kbuf, vtb, ybuf, lam);

  gemm_out<<<dim3(16, 32), 256, 0, stream>>>(ybuf, wob, out, 2048, 2048, 0.2f);
}

// Round 5
// 363.943 us; speedup vs baseline: 2.0907x; 1.0329x over previous
//
#include <hip/hip_runtime.h>
#include <stdint.h>

// ---------------------------------------------------------------------------
// Differential attention, bf16 MFMA pipeline.
// B=2 T=2048 C=2048 H=8 HD=256 HALF=128
// ---------------------------------------------------------------------------

typedef __bf16 bf16;
typedef bf16 bf16x8 __attribute__((ext_vector_type(8)));
typedef bf16 bf16x4 __attribute__((ext_vector_type(4)));
typedef bf16 bf16x2 __attribute__((ext_vector_type(2)));
typedef float f32x4 __attribute__((ext_vector_type(4)));

typedef void __attribute__((address_space(1)))* gas_t;
typedef void __attribute__((address_space(3)))* las_t;

__device__ __forceinline__ void gload16(const void* g, void* l) {
  __builtin_amdgcn_global_load_lds((gas_t)(uintptr_t)g, (las_t)(uint32_t)(uintptr_t)l, 16, 0, 0);
}

__device__ __forceinline__ f32x4 mfma16x16(bf16x8 a, bf16x8 b, f32x4 c) {
  return __builtin_amdgcn_mfma_f32_16x16x32_bf16(a, b, c, 0, 0, 0);
}

// ---------------- cast fp32 -> bf16 ----------------
__global__ __launch_bounds__(256) void cast_f32_bf16(const float* __restrict__ in,
                                                     bf16* __restrict__ out, int n4) {
  int i = blockIdx.x * 256 + threadIdx.x;
  if (i >= n4) return;
  float4 v = ((const float4*)in)[i];
  bf16x4 o;
  o[0] = (bf16)v.x; o[1] = (bf16)v.y; o[2] = (bf16)v.z; o[3] = (bf16)v.w;
  ((bf16x4*)out)[i] = o;
}

// all 4 weight matrices in one launch (blockIdx.y selects)
__global__ __launch_bounds__(256) void cast4_w(const float* __restrict__ a, const float* __restrict__ b,
                                               const float* __restrict__ c, const float* __restrict__ d,
                                               bf16* __restrict__ oa, bf16* __restrict__ ob,
                                               bf16* __restrict__ oc, bf16* __restrict__ od) {
  int w = blockIdx.y;
  const float* in = (w == 0) ? a : (w == 1) ? b : (w == 2) ? c : d;
  bf16* out = (w == 0) ? oa : (w == 1) ? ob : (w == 2) ? oc : od;
  int i = blockIdx.x * 256 + threadIdx.x;
  float4 v = ((const float4*)in)[i];
  bf16x4 o;
  o[0] = (bf16)v.x; o[1] = (bf16)v.y; o[2] = (bf16)v.z; o[3] = (bf16)v.w;
  ((bf16x4*)out)[i] = o;
}

// ---------------- lambda scalar ----------------
__global__ void lambda_kernel(const float* __restrict__ lq1, const float* __restrict__ lk1,
                              const float* __restrict__ lq2, const float* __restrict__ lk2,
                              float* __restrict__ out) {
  __shared__ float red[8];
  int tid = threadIdx.x;
  float a = lq1[tid] * lk1[tid];
  float b = lq2[tid] * lk2[tid];
#pragma unroll
  for (int m = 32; m >= 1; m >>= 1) {
    a += __shfl_xor(a, m, 64);
    b += __shfl_xor(b, m, 64);
  }
  if ((tid & 63) == 0) { red[tid >> 6] = a; red[4 + (tid >> 6)] = b; }
  __syncthreads();
  if (tid == 0) {
    float s1 = red[0] + red[1] + red[2] + red[3];
    float s2 = red[4] + red[5] + red[6] + red[7];
    out[0] = expf(s1) - expf(s2) + 0.8f;
  }
}

// ---------------- pipelined NT GEMM, 256x128 tile, BK=64, 3-deep LDS ----------------
// MODE 0: QKV fused (z=blockIdx.z: 0=Q->rmsnorm, 1=K->rmsnorm, 2=V->transposed)
// MODE 1: out = (A @ Bq^T) * 0.2 (f32)
// 8 waves (4M x 2N), wave tile 64x64. LDS: 3 buffers x (A 32KB + B 16KB),
// fragment-ordered (1KB frag chunks -> conflict-free ds_read_b128).
// Schedule per K-tile t: ONE barrier + ONE counted vmcnt. Stages during t write
// buf[(t+2)%3] (its last readers, tile t-1, completed before bar(t)); reads hit
// buf[t%3] (landed: guaranteed by the vmcnt(6) at end of t-1 = only t+1's 6
// loads left in flight). Compiler is free to interleave reads/MFMA/stages.
template <int MODE>
__global__ __launch_bounds__(512, 2) void gemm_pipe(const bf16* __restrict__ A,
                                                    const bf16* __restrict__ Bq,
                                                    const bf16* __restrict__ Bk,
                                                    const bf16* __restrict__ Bv,
                                                    bf16* __restrict__ Cq, bf16* __restrict__ Ck,
                                                    bf16* __restrict__ Cv,
                                                    float* __restrict__ Cf) {
  __shared__ char lds[147456];  // 3 x 48KB
  const int K = 2048, nt = 32;

  // bijective XCD swizzle (nwg % 8 == 0 in both modes)
  int p = (blockIdx.z * gridDim.y + blockIdx.y) * gridDim.x + blockIdx.x;
  const int nwg = (MODE == 0) ? 768 : 256;
  const int cpx = nwg >> 3;
  int lid = (p & 7) * cpx + (p >> 3);
  const int z = (MODE == 0) ? (lid >> 8) : 0;
  const int rem = lid & 255;
  const int bm = (rem >> 4) * 256, bn = (rem & 15) * 128;
  const bf16* B = (MODE == 1) ? Bq : ((z == 0) ? Bq : ((z == 1) ? Bk : Bv));

  const int tid = threadIdx.x;
  const int wid = tid >> 6, lane = tid & 63;
  const int l15 = lane & 15, lhi = lane >> 4;
  const int wm = wid >> 1, wn = wid & 1;

  // staging bases: lane l -> row +(l&15), k-chunk +(l>>4)*8 (fragment order)
  const bf16* aB = A + (size_t)(bm + l15) * K + lhi * 8;
  const bf16* bB = B + (size_t)(bn + l15) * K + lhi * 8;

  // stage one K-tile (A 32KB: frag g=0..15 x ks=0..1; B 16KB: g=0..7 x ks) -> 6 loads/thread
  auto stage = [&](int t, int pb) {
    char* ab = lds + pb * 49152;
    char* bb2 = ab + 32768;
    const int k0 = t * 64;
    gload16(aB + (size_t)(wid * 16) * K + k0, ab + wid * 1024);
    gload16(aB + (size_t)((wid + 8) * 16) * K + k0, ab + (wid + 8) * 1024);
    gload16(aB + (size_t)(wid * 16) * K + k0 + 32, ab + 16384 + wid * 1024);
    gload16(aB + (size_t)((wid + 8) * 16) * K + k0 + 32, ab + 16384 + (wid + 8) * 1024);
    gload16(bB + (size_t)(wid * 16) * K + k0, bb2 + wid * 1024);
    gload16(bB + (size_t)(wid * 16) * K + k0 + 32, bb2 + 8192 + wid * 1024);
  };

  const f32x4 fz = {0.f, 0.f, 0.f, 0.f};
  f32x4 acc[4][4];
#pragma unroll
  for (int m = 0; m < 4; ++m)
#pragma unroll
    for (int n = 0; n < 4; ++n) acc[m][n] = fz;

  stage(0, 0);
  stage(1, 1);
  asm volatile("s_waitcnt vmcnt(6)" ::: "memory");
  __builtin_amdgcn_s_barrier();

  for (int t = 0; t < nt; ++t) {
    const char* ab = lds + (t % 3) * 49152;
    const char* bb2 = ab + 32768;
    if (t + 2 < nt) stage(t + 2, (t + 2) % 3);
#pragma unroll
    for (int ks = 0; ks < 2; ++ks) {
      bf16x8 a[4], b[4];
#pragma unroll
      for (int m = 0; m < 4; ++m)
        a[m] = *(const bf16x8*)(ab + ks * 16384 + (wm * 4 + m) * 1024 + lane * 16);
#pragma unroll
      for (int n = 0; n < 4; ++n)
        b[n] = *(const bf16x8*)(bb2 + ks * 8192 + (wn * 4 + n) * 1024 + lane * 16);
      __builtin_amdgcn_s_setprio(1);
#pragma unroll
      for (int m = 0; m < 4; ++m)
#pragma unroll
        for (int n = 0; n < 4; ++n) acc[m][n] = mfma16x16(a[m], b[n], acc[m][n]);
      __builtin_amdgcn_s_setprio(0);
    }
    if (t + 2 < nt) {
      asm volatile("s_waitcnt vmcnt(6)" ::: "memory");  // t+1 resident, t+2 in flight
    } else {
      asm volatile("s_waitcnt vmcnt(0)" ::: "memory");
    }
    __builtin_amdgcn_s_barrier();
  }

  // ---- epilogue ----  C/D map: col = lane&15, row = (lane>>4)*4 + r
  if (MODE == 1) {
#pragma unroll
    for (int m = 0; m < 4; ++m)
#pragma unroll
      for (int n = 0; n < 4; ++n)
#pragma unroll
        for (int r = 0; r < 4; ++r) {
          int row = bm + wm * 64 + m * 16 + lhi * 4 + r;
          int col = bn + wn * 64 + n * 16 + l15;
          Cf[(size_t)row * 2048 + col] = acc[m][n][r] * 0.2f;
        }
    return;
  }
  if (z == 2) {  // V -> vtb[b][d][t]
#pragma unroll
    for (int m = 0; m < 4; ++m)
#pragma unroll
      for (int n = 0; n < 4; ++n)
#pragma unroll
        for (int r = 0; r < 4; ++r) {
          int row = bm + wm * 64 + m * 16 + lhi * 4 + r;
          int col = bn + wn * 64 + n * 16 + l15;
          int bb3 = row >> 11, tt = row & 2047;
          Cv[(size_t)bb3 * 2048 * 2048 + (size_t)col * 2048 + tt] = (bf16)acc[m][n][r];
        }
    return;
  }
  // Q/K: rms-norm over this block's 128 cols (= one head-half chunk), f32 accum
  float* ldsf = (float*)lds;  // [256 rows][2 wn]; buffers dead past final barrier
#pragma unroll
  for (int m = 0; m < 4; ++m)
#pragma unroll
    for (int r = 0; r < 4; ++r) {
      float s = 0.f;
#pragma unroll
      for (int n = 0; n < 4; ++n) s += acc[m][n][r] * acc[m][n][r];
      s += __shfl_xor(s, 1, 64);
      s += __shfl_xor(s, 2, 64);
      s += __shfl_xor(s, 4, 64);
      s += __shfl_xor(s, 8, 64);
      if (l15 == 0) ldsf[(wm * 64 + m * 16 + lhi * 4 + r) * 2 + wn] = s;
    }
  __syncthreads();
  const float osc = (z == 0) ? 0.08838834764831845f : 1.0f;  // fold 1/sqrt(128) into q
  bf16* C = (z == 0) ? Cq : Ck;
#pragma unroll
  for (int m = 0; m < 4; ++m)
#pragma unroll
    for (int r = 0; r < 4; ++r) {
      int rl = wm * 64 + m * 16 + lhi * 4 + r;
      float tot = ldsf[rl * 2] + ldsf[rl * 2 + 1];
      float sc = rsqrtf(tot * (1.0f / 128.0f) + 1.1920929e-07f) * osc;
#pragma unroll
      for (int n = 0; n < 4; ++n) {
        int col = bn + wn * 64 + n * 16 + l15;
        C[(size_t)(bm + rl) * 2048 + col] = (bf16)(acc[m][n][r] * sc);
      }
    }
}

// ---------------- dual-stream causal flash attention ----------------
__global__ __launch_bounds__(256) void attn_kernel(const bf16* __restrict__ qb, const bf16* __restrict__ kb,
                                                   const bf16* __restrict__ vtb, bf16* __restrict__ yb,
                                                   const float* __restrict__ lamp) {
  __shared__ char lds[53248];
  const int tid = threadIdx.x;
  const int wid = tid >> 6, lane = tid & 63;
  const int l15 = lane & 15, lhi = lane >> 4;
  char* vtl = lds + 32768;
  char* pbf = lds + 49152 + wid * 1024;
  const int qt = 31 - blockIdx.y;
  const int bh = blockIdx.x;
  const int b = bh >> 3, h = bh & 7;
  const int qr0 = qt * 64 + wid * 16;
  const float lam = lamp[0];

  const bf16* qrow = qb + (size_t)(b * 2048 + qr0 + l15) * 2048 + h * 256 + lhi * 8;
  bf16x8 q1f[4], q2f[4];
#pragma unroll
  for (int s = 0; s < 4; ++s) {
    q1f[s] = *(const bf16x8*)(qrow + s * 32);
    q2f[s] = *(const bf16x8*)(qrow + 128 + s * 32);
  }

  const f32x4 fz = {0.f, 0.f, 0.f, 0.f};
  f32x4 y1[16], y2[16];
#pragma unroll
  for (int f = 0; f < 16; ++f) { y1[f] = fz; y2[f] = fz; }
  float l1[4] = {0.f, 0.f, 0.f, 0.f}, l2[4] = {0.f, 0.f, 0.f, 0.f};

  const int nkt = 2 * qt + 2;
  const bf16* kbase = kb + (size_t)(b * 2048) * 2048 + h * 256;
  const bf16* vbase = vtb + (size_t)b * 2048 * 2048 + (size_t)(h * 256) * 2048;

  auto stageK = [&](int kt2, int p) {
    const int t0 = kt2 * 32;
    char* kd = lds + p * 16384 + wid * 1024;
    const bf16* sp = kbase + (size_t)(t0 + l15) * 2048 + wid * 32 + lhi * 8;
    gload16(sp, kd);
    gload16(sp + 16 * 2048, kd + 4096);
    gload16(sp + 128, kd + 8192);
    gload16(sp + 16 * 2048 + 128, kd + 12288);
  };
  auto stageVT = [&](int kt2) {
    const int t0 = kt2 * 32;
    const bf16* vp = vbase + (size_t)(wid * 16 + l15) * 2048 + t0 + lhi * 8;
#pragma unroll
    for (int i = 0; i < 4; ++i)
      gload16(vp + (size_t)i * 64 * 2048, vtl + (i * 4 + wid) * 1024);
  };

  stageK(0, 0);
  stageVT(0);
  __syncthreads();

  for (int kt = 0; kt < nkt; ++kt) {
    const int cur = kt & 1;
    const int t0 = kt * 32;
    const bool active = (t0 <= qr0 + 15);
    f32x4 s1g[2], s2g[2];
    if (active) {
      const char* kc = lds + cur * 16384;
#pragma unroll
      for (int g = 0; g < 2; ++g) {
        f32x4 a1 = fz, a2 = fz;
#pragma unroll
        for (int s = 0; s < 4; ++s) {
          a1 = mfma16x16(q1f[s], *(const bf16x8*)(kc + ((g * 4 + s) * 64 + lane) * 16), a1);
          a2 = mfma16x16(q2f[s], *(const bf16x8*)(kc + 8192 + ((g * 4 + s) * 64 + lane) * 16), a2);
        }
        s1g[g] = a1;
        s2g[g] = a2;
      }
      if (t0 + 31 > qr0) {
#pragma unroll
        for (int g = 0; g < 2; ++g) {
          int col = t0 + g * 16 + l15;
#pragma unroll
          for (int r = 0; r < 4; ++r) {
            int row = qr0 + lhi * 4 + r;
            if (col > row) { s1g[g][r] = -1e30f; s2g[g][r] = -1e30f; }
          }
        }
      }
#pragma unroll
      for (int g = 0; g < 2; ++g) {
#pragma unroll
        for (int r = 0; r < 4; ++r) {
          float p1 = __expf(s1g[g][r] - 12.0f);
          float p2 = __expf(s2g[g][r] - 12.0f);
          l1[r] += p1;
          l2[r] += p2;
          *(bf16*)(pbf + ((lhi * 4 + r) * 32 + g * 16 + l15) * 2) = (bf16)p1;
          s2g[g][r] = p2;
        }
      }
    }
    __syncthreads();
    if (active) {
      bf16x8 pa1 = *(const bf16x8*)(pbf + (l15 * 32 + lhi * 8) * 2);
#pragma unroll
      for (int f = 0; f < 16; ++f)
        y1[f] = mfma16x16(pa1, *(const bf16x8*)(vtl + (f * 64 + lane) * 16), y1[f]);
#pragma unroll
      for (int g = 0; g < 2; ++g)
#pragma unroll
        for (int r = 0; r < 4; ++r)
          *(bf16*)(pbf + ((lhi * 4 + r) * 32 + g * 16 + l15) * 2) = (bf16)s2g[g][r];
      bf16x8 pa2 = *(const bf16x8*)(pbf + (l15 * 32 + lhi * 8) * 2);
#pragma unroll
      for (int f = 0; f < 16; ++f)
        y2[f] = mfma16x16(pa2, *(const bf16x8*)(vtl + (f * 64 + lane) * 16), y2[f]);
    }
    __syncthreads();
    if (kt + 1 < nkt) {
      stageK(kt + 1, cur ^ 1);
      stageVT(kt + 1);
    }
  }

#pragma unroll
  for (int r = 0; r < 4; ++r) {
    float s1 = l1[r], s2 = l2[r];
#pragma unroll
    for (int m = 1; m <= 8; m <<= 1) {
      s1 += __shfl_xor(s1, m, 64);
      s2 += __shfl_xor(s2, m, 64);
    }
    float inv1 = 1.f / s1;
    float inv2 = lam / s2;
    int row = qr0 + lhi * 4 + r;
    bf16* orow = yb + (size_t)(b * 2048 + row) * 2048 + h * 256 + l15;
#pragma unroll
    for (int f = 0; f < 16; ++f) {
      float v = y1[f][r] * inv1 - y2[f][r] * inv2;
      orow[f * 16] = (bf16)v;
    }
  }
}

// ---------------------------------------------------------------------------
extern "C" void kernel_launch(void* const* d_in, const int* in_sizes, int n_in,
                              void* d_out, int out_size, void* d_ws, size_t ws_size,
                              hipStream_t stream) {
  const float* x = (const float*)d_in[0];
  const float* wq = (const float*)d_in[1];
  const float* wk = (const float*)d_in[2];
  const float* wv = (const float*)d_in[3];
  const float* wo = (const float*)d_in[4];
  const float* lq1 = (const float*)d_in[5];
  const float* lk1 = (const float*)d_in[6];
  const float* lq2 = (const float*)d_in[7];
  const float* lk2 = (const float*)d_in[8];
  float* out = (float*)d_out;
  char* ws = (char*)d_ws;

  if (ws_size < 117440516) return;

  bf16* xb = (bf16*)(ws + 0);             // [4096][2048]
  bf16* wqb = (bf16*)(ws + 16777216);     // [2048][2048]
  bf16* wkb = (bf16*)(ws + 25165824);
  bf16* wvb = (bf16*)(ws + 33554432);
  bf16* wob = (bf16*)(ws + 41943040);
  bf16* qbuf = (bf16*)(ws + 50331648);    // [4096][2048]
  bf16* kbuf = (bf16*)(ws + 67108864);    // [4096][2048]
  bf16* vtb = (bf16*)(ws + 83886080);     // [2][2048 d][2048 t]
  bf16* ybuf = (bf16*)(ws + 100663296);   // [4096][2048]
  float* lam = (float*)(ws + 117440512);

  cast_f32_bf16<<<8192, 256, 0, stream>>>(x, xb, 2097152);
  cast4_w<<<dim3(4096, 4), 256, 0, stream>>>(wq, wk, wv, wo, wqb, wkb, wvb, wob);
  lambda_kernel<<<1, 256, 0, stream>>>(lq1, lk1, lq2, lk2, lam);

  gemm_pipe<0><<<dim3(16, 16, 3), 512, 0, stream>>>(xb, wqb, wkb, wvb, qbuf, kbuf, vtb, nullptr);

  attn_kernel<<<dim3(16, 32), 256, 0, stream>>>(qbuf, kbuf, vtb, ybuf, lam);

  gemm_pipe<1><<<dim3(16, 16, 1), 512, 0, stream>>>(ybuf, wob, nullptr, nullptr, nullptr, nullptr, nullptr, out);
}

// Round 6
// 359.482 us; speedup vs baseline: 2.1166x; 1.0124x over previous
//
#include <hip/hip_runtime.h>
#include <stdint.h>

// ---------------------------------------------------------------------------
// Differential attention, bf16 MFMA pipeline.
// B=2 T=2048 C=2048 H=8 HD=256 HALF=128
// ---------------------------------------------------------------------------

typedef __bf16 bf16;
typedef bf16 bf16x8 __attribute__((ext_vector_type(8)));
typedef bf16 bf16x4 __attribute__((ext_vector_type(4)));
typedef bf16 bf16x2 __attribute__((ext_vector_type(2)));
typedef float f32x4 __attribute__((ext_vector_type(4)));

typedef void __attribute__((address_space(1)))* gas_t;
typedef void __attribute__((address_space(3)))* las_t;

__device__ __forceinline__ void gload16(const void* g, void* l) {
  __builtin_amdgcn_global_load_lds((gas_t)(uintptr_t)g, (las_t)(uint32_t)(uintptr_t)l, 16, 0, 0);
}

__device__ __forceinline__ f32x4 mfma16x16(bf16x8 a, bf16x8 b, f32x4 c) {
  return __builtin_amdgcn_mfma_f32_16x16x32_bf16(a, b, c, 0, 0, 0);
}

// ---------------- cast fp32 -> bf16 ----------------
__global__ __launch_bounds__(256) void cast_f32_bf16(const float* __restrict__ in,
                                                     bf16* __restrict__ out, int n4) {
  int i = blockIdx.x * 256 + threadIdx.x;
  if (i >= n4) return;
  float4 v = ((const float4*)in)[i];
  bf16x4 o;
  o[0] = (bf16)v.x; o[1] = (bf16)v.y; o[2] = (bf16)v.z; o[3] = (bf16)v.w;
  ((bf16x4*)out)[i] = o;
}

// all 4 weight matrices in one launch (blockIdx.y selects)
__global__ __launch_bounds__(256) void cast4_w(const float* __restrict__ a, const float* __restrict__ b,
                                               const float* __restrict__ c, const float* __restrict__ d,
                                               bf16* __restrict__ oa, bf16* __restrict__ ob,
                                               bf16* __restrict__ oc, bf16* __restrict__ od) {
  int w = blockIdx.y;
  const float* in = (w == 0) ? a : (w == 1) ? b : (w == 2) ? c : d;
  bf16* out = (w == 0) ? oa : (w == 1) ? ob : (w == 2) ? oc : od;
  int i = blockIdx.x * 256 + threadIdx.x;
  float4 v = ((const float4*)in)[i];
  bf16x4 o;
  o[0] = (bf16)v.x; o[1] = (bf16)v.y; o[2] = (bf16)v.z; o[3] = (bf16)v.w;
  ((bf16x4*)out)[i] = o;
}

// ---------------- lambda scalar ----------------
__global__ void lambda_kernel(const float* __restrict__ lq1, const float* __restrict__ lk1,
                              const float* __restrict__ lq2, const float* __restrict__ lk2,
                              float* __restrict__ out) {
  __shared__ float red[8];
  int tid = threadIdx.x;
  float a = lq1[tid] * lk1[tid];
  float b = lq2[tid] * lk2[tid];
#pragma unroll
  for (int m = 32; m >= 1; m >>= 1) {
    a += __shfl_xor(a, m, 64);
    b += __shfl_xor(b, m, 64);
  }
  if ((tid & 63) == 0) { red[tid >> 6] = a; red[4 + (tid >> 6)] = b; }
  __syncthreads();
  if (tid == 0) {
    float s1 = red[0] + red[1] + red[2] + red[3];
    float s2 = red[4] + red[5] + red[6] + red[7];
    out[0] = expf(s1) - expf(s2) + 0.8f;
  }
}

// ---------------- pipelined NT GEMM, 256x128 tile, BK=32, 3-deep LDS ----------------
// MODE 0: fused QKV as one GEMM over N=6144 (col region selects Wq/Wk/Wv and epilogue:
//         Q->rmsnorm, K->rmsnorm, V->transposed vtb[b][d][t]).
// MODE 1: out = (A @ Bq^T) * 0.2 (f32)
// 4 waves (2M x 2N), wave tile 128x64 (42.7 MFMA-FLOP per LDS byte vs 32 for 64x64 --
// this kernel is LDS-BW-bound, wave tile is the lever). 3 buffers x 24KB = 72KB ->
// 2 blocks/CU for cross-block latency hiding. Fragment-ordered LDS (1KB frags,
// conflict-free contiguous wave reads, 0 bank conflicts measured r3-r5).
// Sync per K-tile t (proven r5): stage(t+2)->buf[(t+2)%3]; read buf[t%3]; MFMA;
// vmcnt(6) (drains stage(t+1), leaves t+2 in flight); barrier.
template <int MODE>
__global__ __launch_bounds__(256, 2) void gemm_pipe(const bf16* __restrict__ A,
                                                    const bf16* __restrict__ Bq,
                                                    const bf16* __restrict__ Bk,
                                                    const bf16* __restrict__ Bv,
                                                    bf16* __restrict__ Cq, bf16* __restrict__ Ck,
                                                    bf16* __restrict__ Cv,
                                                    float* __restrict__ Cf) {
  __shared__ char lds[73728];  // 3 x 24KB
  const int K = 2048, nt = 64;

  // bijective XCD swizzle (nwg % 8 == 0 in both modes)
  int p = blockIdx.y * gridDim.x + blockIdx.x;
  const int nwg = (MODE == 0) ? 768 : 256;
  const int cpx = nwg >> 3;
  int lid = (p & 7) * cpx + (p >> 3);
  const int ntn = (MODE == 0) ? 48 : 16;  // N tiles of 128
  const int bm = (lid / ntn) * 256;
  const int bnG = (lid % ntn) * 128;            // global col in [0, 6144) / [0, 2048)
  const int z = (MODE == 0) ? (bnG >> 11) : 0;  // weight region
  const int bn = bnG & 2047;                    // col within region
  const bf16* B = (MODE == 1) ? Bq : ((z == 0) ? Bq : ((z == 1) ? Bk : Bv));

  const int tid = threadIdx.x;
  const int wid = tid >> 6, lane = tid & 63;
  const int l15 = lane & 15, lhi = lane >> 4;
  const int wm = wid >> 1, wn = wid & 1;

  // staging bases: lane l -> row +(l&15), k-chunk +(l>>4)*8 (fragment order)
  const bf16* aB = A + (size_t)(bm + l15) * K + lhi * 8;
  const bf16* bB = B + (size_t)(bn + l15) * K + lhi * 8;

  // one K-tile = A 16KB (16 frags) + B 8KB (8 frags); 6 gloads/thread.
  // group g covers frags g*4+wid; frag f = 16 rows/cols starting at f*16.
  auto stage = [&](int t, int pb) {
    char* base = lds + pb * 24576;
    const int k0 = t * 32;
    gload16(aB + (size_t)((0 + wid) * 16) * K + k0, base + wid * 1024);
    gload16(aB + (size_t)((4 + wid) * 16) * K + k0, base + 4096 + wid * 1024);
    gload16(aB + (size_t)((8 + wid) * 16) * K + k0, base + 8192 + wid * 1024);
    gload16(aB + (size_t)((12 + wid) * 16) * K + k0, base + 12288 + wid * 1024);
    gload16(bB + (size_t)((0 + wid) * 16) * K + k0, base + 16384 + wid * 1024);
    gload16(bB + (size_t)((4 + wid) * 16) * K + k0, base + 20480 + wid * 1024);
  };

  const f32x4 fz = {0.f, 0.f, 0.f, 0.f};
  f32x4 acc[8][4];
#pragma unroll
  for (int m = 0; m < 8; ++m)
#pragma unroll
    for (int n = 0; n < 4; ++n) acc[m][n] = fz;

  stage(0, 0);
  stage(1, 1);
  asm volatile("s_waitcnt vmcnt(6)" ::: "memory");
  __builtin_amdgcn_s_barrier();

  for (int t = 0; t < nt; ++t) {
    const char* ab = lds + (t % 3) * 24576;
    if (t + 2 < nt) stage(t + 2, (t + 2) % 3);
    bf16x8 a[8], b[4];
#pragma unroll
    for (int m = 0; m < 8; ++m)
      a[m] = *(const bf16x8*)(ab + (wm * 8 + m) * 1024 + lane * 16);
#pragma unroll
    for (int n = 0; n < 4; ++n)
      b[n] = *(const bf16x8*)(ab + 16384 + (wn * 4 + n) * 1024 + lane * 16);
    __builtin_amdgcn_s_setprio(1);
#pragma unroll
    for (int m = 0; m < 8; ++m)
#pragma unroll
      for (int n = 0; n < 4; ++n) acc[m][n] = mfma16x16(a[m], b[n], acc[m][n]);
    __builtin_amdgcn_s_setprio(0);
    if (t + 2 < nt) {
      asm volatile("s_waitcnt vmcnt(6)" ::: "memory");  // t+1 resident, t+2 in flight
    } else {
      asm volatile("s_waitcnt vmcnt(0)" ::: "memory");
    }
    __builtin_amdgcn_s_barrier();
  }

  // ---- epilogue ----  C/D map: col = lane&15, row = (lane>>4)*4 + r
  if (MODE == 1) {
#pragma unroll
    for (int m = 0; m < 8; ++m)
#pragma unroll
      for (int n = 0; n < 4; ++n)
#pragma unroll
        for (int r = 0; r < 4; ++r) {
          int row = bm + wm * 128 + m * 16 + lhi * 4 + r;
          int col = bnG + wn * 64 + n * 16 + l15;
          Cf[(size_t)row * 2048 + col] = acc[m][n][r] * 0.2f;
        }
    return;
  }
  if (z == 2) {  // V -> vtb[b][d][t]
#pragma unroll
    for (int m = 0; m < 8; ++m)
#pragma unroll
      for (int n = 0; n < 4; ++n)
#pragma unroll
        for (int r = 0; r < 4; ++r) {
          int row = bm + wm * 128 + m * 16 + lhi * 4 + r;
          int d = bn + wn * 64 + n * 16 + l15;
          int bb3 = row >> 11, tt = row & 2047;
          Cv[(size_t)bb3 * 2048 * 2048 + (size_t)d * 2048 + tt] = (bf16)acc[m][n][r];
        }
    return;
  }
  // Q/K: rms-norm over this block's 128 cols (exactly one head-half chunk), f32 accum
  float* ldsf = (float*)lds;  // [256 rows][2 wn] partials; buffers dead past final barrier
#pragma unroll
  for (int m = 0; m < 8; ++m)
#pragma unroll
    for (int r = 0; r < 4; ++r) {
      float s = 0.f;
#pragma unroll
      for (int n = 0; n < 4; ++n) s += acc[m][n][r] * acc[m][n][r];
      s += __shfl_xor(s, 1, 64);
      s += __shfl_xor(s, 2, 64);
      s += __shfl_xor(s, 4, 64);
      s += __shfl_xor(s, 8, 64);
      if (l15 == 0) ldsf[(wm * 128 + m * 16 + lhi * 4 + r) * 2 + wn] = s;
    }
  __syncthreads();
  const float osc = (z == 0) ? 0.08838834764831845f : 1.0f;  // fold 1/sqrt(128) into q
  bf16* C = (z == 0) ? Cq : Ck;
#pragma unroll
  for (int m = 0; m < 8; ++m)
#pragma unroll
    for (int r = 0; r < 4; ++r) {
      int rl = wm * 128 + m * 16 + lhi * 4 + r;
      float tot = ldsf[rl * 2] + ldsf[rl * 2 + 1];
      float sc = rsqrtf(tot * (1.0f / 128.0f) + 1.1920929e-07f) * osc;
#pragma unroll
      for (int n = 0; n < 4; ++n) {
        int col = bn + wn * 64 + n * 16 + l15;
        C[(size_t)(bm + rl) * 2048 + col] = (bf16)(acc[m][n][r] * sc);
      }
    }
}

// ---------------- dual-stream causal flash attention ----------------
__global__ __launch_bounds__(256) void attn_kernel(const bf16* __restrict__ qb, const bf16* __restrict__ kb,
                                                   const bf16* __restrict__ vtb, bf16* __restrict__ yb,
                                                   const float* __restrict__ lamp) {
  __shared__ char lds[53248];
  const int tid = threadIdx.x;
  const int wid = tid >> 6, lane = tid & 63;
  const int l15 = lane & 15, lhi = lane >> 4;
  char* vtl = lds + 32768;
  char* pbf = lds + 49152 + wid * 1024;
  const int qt = 31 - blockIdx.y;
  const int bh = blockIdx.x;
  const int b = bh >> 3, h = bh & 7;
  const int qr0 = qt * 64 + wid * 16;
  const float lam = lamp[0];

  const bf16* qrow = qb + (size_t)(b * 2048 + qr0 + l15) * 2048 + h * 256 + lhi * 8;
  bf16x8 q1f[4], q2f[4];
#pragma unroll
  for (int s = 0; s < 4; ++s) {
    q1f[s] = *(const bf16x8*)(qrow + s * 32);
    q2f[s] = *(const bf16x8*)(qrow + 128 + s * 32);
  }

  const f32x4 fz = {0.f, 0.f, 0.f, 0.f};
  f32x4 y1[16], y2[16];
#pragma unroll
  for (int f = 0; f < 16; ++f) { y1[f] = fz; y2[f] = fz; }
  float l1[4] = {0.f, 0.f, 0.f, 0.f}, l2[4] = {0.f, 0.f, 0.f, 0.f};

  const int nkt = 2 * qt + 2;
  const bf16* kbase = kb + (size_t)(b * 2048) * 2048 + h * 256;
  const bf16* vbase = vtb + (size_t)b * 2048 * 2048 + (size_t)(h * 256) * 2048;

  auto stageK = [&](int kt2, int p) {
    const int t0 = kt2 * 32;
    char* kd = lds + p * 16384 + wid * 1024;
    const bf16* sp = kbase + (size_t)(t0 + l15) * 2048 + wid * 32 + lhi * 8;
    gload16(sp, kd);
    gload16(sp + 16 * 2048, kd + 4096);
    gload16(sp + 128, kd + 8192);
    gload16(sp + 16 * 2048 + 128, kd + 12288);
  };
  auto stageVT = [&](int kt2) {
    const int t0 = kt2 * 32;
    const bf16* vp = vbase + (size_t)(wid * 16 + l15) * 2048 + t0 + lhi * 8;
#pragma unroll
    for (int i = 0; i < 4; ++i)
      gload16(vp + (size_t)i * 64 * 2048, vtl + (i * 4 + wid) * 1024);
  };

  stageK(0, 0);
  stageVT(0);
  __syncthreads();

  for (int kt = 0; kt < nkt; ++kt) {
    const int cur = kt & 1;
    const int t0 = kt * 32;
    const bool active = (t0 <= qr0 + 15);
    f32x4 s1g[2], s2g[2];
    if (active) {
      const char* kc = lds + cur * 16384;
#pragma unroll
      for (int g = 0; g < 2; ++g) {
        f32x4 a1 = fz, a2 = fz;
#pragma unroll
        for (int s = 0; s < 4; ++s) {
          a1 = mfma16x16(q1f[s], *(const bf16x8*)(kc + ((g * 4 + s) * 64 + lane) * 16), a1);
          a2 = mfma16x16(q2f[s], *(const bf16x8*)(kc + 8192 + ((g * 4 + s) * 64 + lane) * 16), a2);
        }
        s1g[g] = a1;
        s2g[g] = a2;
      }
      if (t0 + 31 > qr0) {
#pragma unroll
        for (int g = 0; g < 2; ++g) {
          int col = t0 + g * 16 + l15;
#pragma unroll
          for (int r = 0; r < 4; ++r) {
            int row = qr0 + lhi * 4 + r;
            if (col > row) { s1g[g][r] = -1e30f; s2g[g][r] = -1e30f; }
          }
        }
      }
#pragma unroll
      for (int g = 0; g < 2; ++g) {
#pragma unroll
        for (int r = 0; r < 4; ++r) {
          float p1 = __expf(s1g[g][r] - 12.0f);
          float p2 = __expf(s2g[g][r] - 12.0f);
          l1[r] += p1;
          l2[r] += p2;
          *(bf16*)(pbf + ((lhi * 4 + r) * 32 + g * 16 + l15) * 2) = (bf16)p1;
          s2g[g][r] = p2;
        }
      }
    }
    __syncthreads();
    if (active) {
      bf16x8 pa1 = *(const bf16x8*)(pbf + (l15 * 32 + lhi * 8) * 2);
#pragma unroll
      for (int f = 0; f < 16; ++f)
        y1[f] = mfma16x16(pa1, *(const bf16x8*)(vtl + (f * 64 + lane) * 16), y1[f]);
#pragma unroll
      for (int g = 0; g < 2; ++g)
#pragma unroll
        for (int r = 0; r < 4; ++r)
          *(bf16*)(pbf + ((lhi * 4 + r) * 32 + g * 16 + l15) * 2) = (bf16)s2g[g][r];
      bf16x8 pa2 = *(const bf16x8*)(pbf + (l15 * 32 + lhi * 8) * 2);
#pragma unroll
      for (int f = 0; f < 16; ++f)
        y2[f] = mfma16x16(pa2, *(const bf16x8*)(vtl + (f * 64 + lane) * 16), y2[f]);
    }
    __syncthreads();
    if (kt + 1 < nkt) {
      stageK(kt + 1, cur ^ 1);
      stageVT(kt + 1);
    }
  }

#pragma unroll
  for (int r = 0; r < 4; ++r) {
    float s1 = l1[r], s2 = l2[r];
#pragma unroll
    for (int m = 1; m <= 8; m <<= 1) {
      s1 += __shfl_xor(s1, m, 64);
      s2 += __shfl_xor(s2, m, 64);
    }
    float inv1 = 1.f / s1;
    float inv2 = lam / s2;
    int row = qr0 + lhi * 4 + r;
    bf16* orow = yb + (size_t)(b * 2048 + row) * 2048 + h * 256 + l15;
#pragma unroll
    for (int f = 0; f < 16; ++f) {
      float v = y1[f][r] * inv1 - y2[f][r] * inv2;
      orow[f * 16] = (bf16)v;
    }
  }
}

// ---------------------------------------------------------------------------
extern "C" void kernel_launch(void* const* d_in, const int* in_sizes, int n_in,
                              void* d_out, int out_size, void* d_ws, size_t ws_size,
                              hipStream_t stream) {
  const float* x = (const float*)d_in[0];
  const float* wq = (const float*)d_in[1];
  const float* wk = (const float*)d_in[2];
  const float* wv = (const float*)d_in[3];
  const float* wo = (const float*)d_in[4];
  const float* lq1 = (const float*)d_in[5];
  const float* lk1 = (const float*)d_in[6];
  const float* lq2 = (const float*)d_in[7];
  const float* lk2 = (const float*)d_in[8];
  float* out = (float*)d_out;
  char* ws = (char*)d_ws;

  if (ws_size < 117440516) return;

  bf16* xb = (bf16*)(ws + 0);             // [4096][2048]
  bf16* wqb = (bf16*)(ws + 16777216);     // [2048][2048]
  bf16* wkb = (bf16*)(ws + 25165824);
  bf16* wvb = (bf16*)(ws + 33554432);
  bf16* wob = (bf16*)(ws + 41943040);
  bf16* qbuf = (bf16*)(ws + 50331648);    // [4096][2048]
  bf16* kbuf = (bf16*)(ws + 67108864);    // [4096][2048]
  bf16* vtb = (bf16*)(ws + 83886080);     // [2][2048 d][2048 t]
  bf16* ybuf = (bf16*)(ws + 100663296);   // [4096][2048]
  float* lam = (float*)(ws + 117440512);

  cast_f32_bf16<<<8192, 256, 0, stream>>>(x, xb, 2097152);
  cast4_w<<<dim3(4096, 4), 256, 0, stream>>>(wq, wk, wv, wo, wqb, wkb, wvb, wob);
  lambda_kernel<<<1, 256, 0, stream>>>(lq1, lk1, lq2, lk2, lam);

  gemm_pipe<0><<<dim3(48, 16), 256, 0, stream>>>(xb, wqb, wkb, wvb, qbuf, kbuf, vtb, nullptr);

  attn_kernel<<<dim3(16, 32), 256, 0, stream>>>(qbuf, kbuf, vtb, ybuf, lam);

  gemm_pipe<1><<<dim3(16, 16), 256, 0, stream>>>(ybuf, wob, nullptr, nullptr, nullptr, nullptr, nullptr, out);
}

// Round 7
// 350.617 us; speedup vs baseline: 2.1701x; 1.0253x over previous
//
#include <hip/hip_runtime.h>
#include <stdint.h>

// ---------------------------------------------------------------------------
// Differential attention, bf16 MFMA pipeline.
// B=2 T=2048 C=2048 H=8 HD=256 HALF=128
// ---------------------------------------------------------------------------

typedef __bf16 bf16;
typedef bf16 bf16x8 __attribute__((ext_vector_type(8)));
typedef bf16 bf16x4 __attribute__((ext_vector_type(4)));
typedef bf16 bf16x2 __attribute__((ext_vector_type(2)));
typedef float f32x4 __attribute__((ext_vector_type(4)));

typedef void __attribute__((address_space(1)))* gas_t;
typedef void __attribute__((address_space(3)))* las_t;

__device__ __forceinline__ void gload16(const void* g, void* l) {
  __builtin_amdgcn_global_load_lds((gas_t)(uintptr_t)g, (las_t)(uint32_t)(uintptr_t)l, 16, 0, 0);
}

__device__ __forceinline__ f32x4 mfma16x16(bf16x8 a, bf16x8 b, f32x4 c) {
  return __builtin_amdgcn_mfma_f32_16x16x32_bf16(a, b, c, 0, 0, 0);
}

// ---------------- cast fp32 -> bf16 ----------------
__global__ __launch_bounds__(256) void cast_f32_bf16(const float* __restrict__ in,
                                                     bf16* __restrict__ out, int n4) {
  int i = blockIdx.x * 256 + threadIdx.x;
  if (i >= n4) return;
  float4 v = ((const float4*)in)[i];
  bf16x4 o;
  o[0] = (bf16)v.x; o[1] = (bf16)v.y; o[2] = (bf16)v.z; o[3] = (bf16)v.w;
  ((bf16x4*)out)[i] = o;
}

__global__ __launch_bounds__(256) void cast4_w(const float* __restrict__ a, const float* __restrict__ b,
                                               const float* __restrict__ c, const float* __restrict__ d,
                                               bf16* __restrict__ oa, bf16* __restrict__ ob,
                                               bf16* __restrict__ oc, bf16* __restrict__ od) {
  int w = blockIdx.y;
  const float* in = (w == 0) ? a : (w == 1) ? b : (w == 2) ? c : d;
  bf16* out = (w == 0) ? oa : (w == 1) ? ob : (w == 2) ? oc : od;
  int i = blockIdx.x * 256 + threadIdx.x;
  float4 v = ((const float4*)in)[i];
  bf16x4 o;
  o[0] = (bf16)v.x; o[1] = (bf16)v.y; o[2] = (bf16)v.z; o[3] = (bf16)v.w;
  ((bf16x4*)out)[i] = o;
}

// ---------------- lambda scalar ----------------
__global__ void lambda_kernel(const float* __restrict__ lq1, const float* __restrict__ lk1,
                              const float* __restrict__ lq2, const float* __restrict__ lk2,
                              float* __restrict__ out) {
  __shared__ float red[8];
  int tid = threadIdx.x;
  float a = lq1[tid] * lk1[tid];
  float b = lq2[tid] * lk2[tid];
#pragma unroll
  for (int m = 32; m >= 1; m >>= 1) {
    a += __shfl_xor(a, m, 64);
    b += __shfl_xor(b, m, 64);
  }
  if ((tid & 63) == 0) { red[tid >> 6] = a; red[4 + (tid >> 6)] = b; }
  __syncthreads();
  if (tid == 0) {
    float s1 = red[0] + red[1] + red[2] + red[3];
    float s2 = red[4] + red[5] + red[6] + red[7];
    out[0] = expf(s1) - expf(s2) + 0.8f;
  }
}

// ---------------- QKV GEMM: m201-style 8-phase, 256x256 tile, BK=32 ----------------
// One GEMM over N=6144 (col region -> Wq/Wk/Wv + epilogue select).
// 8 waves (2M x 4N), wave tile 128x64, acc[8][4]. 3 LDS buffers x 32KB = 96KB,
// fragment-ordered (1KB frags -> conflict-free contiguous wave ds_read_b128).
// Per K-tile t, TWO phases of {ds_read ; 2 gload stages -> buf[(t+2)%3] ; bar ;
// setprio(1) ; 16 MFMA ; setprio(0) ; bar}, counted vmcnt(4) once per tile
// (keeps exactly t+2's 4 loads in flight; t+1 resident at its first read).
// 3-buffer invariant: stage target was last read in tile t-1, whose reads all
// completed before the tile-(t-1) closing barrier -> no intra-tile hazards.
__global__ __launch_bounds__(512, 2) void gemm_qkv8(const bf16* __restrict__ A,
                                                    const bf16* __restrict__ Bq,
                                                    const bf16* __restrict__ Bk,
                                                    const bf16* __restrict__ Bv,
                                                    bf16* __restrict__ Cq, bf16* __restrict__ Ck,
                                                    bf16* __restrict__ Cv) {
  __shared__ char lds[98304];  // 3 x (A 16KB + B 16KB)
  const int K = 2048, nt = 64;

  // bijective XCD swizzle over 384 blocks (384 % 8 == 0)
  int p = blockIdx.y * gridDim.x + blockIdx.x;
  int lid = (p & 7) * 48 + (p >> 3);
  const int bm = (lid / 24) * 256;
  const int bnG = (lid % 24) * 256;   // [0, 6144)
  const int z = bnG >> 11;            // weight region (256 | 2048 -> no straddle)
  const int bn = bnG & 2047;
  const bf16* B = (z == 0) ? Bq : ((z == 1) ? Bk : Bv);

  const int tid = threadIdx.x;
  const int wid = tid >> 6, lane = tid & 63;
  const int l15 = lane & 15, lhi = lane >> 4;
  const int wm = wid >> 2, wn = wid & 3;

  // staging: frag f = c*8+wid covers rows/cols f*16..f*16+15; lane -> (row l15, kchunk lhi)
  const bf16* aS0 = A + (size_t)(bm + wid * 16 + l15) * K + lhi * 8;
  const bf16* bS0 = B + (size_t)(bn + wid * 16 + l15) * K + lhi * 8;

  auto stA = [&](int t, int pb) {  // 2 vmem instrs
    char* d = lds + pb * 32768 + wid * 1024;
    const bf16* s = aS0 + t * 32;
    gload16(s, d);
    gload16(s + (size_t)128 * K, d + 8192);
  };
  auto stB = [&](int t, int pb) {  // 2 vmem instrs
    char* d = lds + pb * 32768 + 16384 + wid * 1024;
    const bf16* s = bS0 + t * 32;
    gload16(s, d);
    gload16(s + (size_t)128 * K, d + 8192);
  };

  const f32x4 fz = {0.f, 0.f, 0.f, 0.f};
  f32x4 acc[8][4];
#pragma unroll
  for (int m = 0; m < 8; ++m)
#pragma unroll
    for (int n = 0; n < 4; ++n) acc[m][n] = fz;

  // prologue: tiles 0,1 staged; drain to 4 (= tile1's loads) so tile0 is resident
  stA(0, 0); stB(0, 0);
  stA(1, 1); stB(1, 1);
  asm volatile("s_waitcnt vmcnt(4)" ::: "memory");
  __builtin_amdgcn_s_barrier();

  int cur = 0;
  for (int t = 0; t < nt; ++t) {
    const char* ab = lds + cur * 32768;
    const char* bb = ab + 16384;
    int nx2 = cur + 2; if (nx2 >= 3) nx2 -= 3;
    bf16x8 a[8], b0, b1;

    // ---- phase A: n-half 0 ----
#pragma unroll
    for (int m = 0; m < 8; ++m) a[m] = *(const bf16x8*)(ab + (wm * 8 + m) * 1024 + lane * 16);
    b0 = *(const bf16x8*)(bb + (wn * 4 + 0) * 1024 + lane * 16);
    b1 = *(const bf16x8*)(bb + (wn * 4 + 1) * 1024 + lane * 16);
    if (t + 2 < nt) stA(t + 2, nx2);
    __builtin_amdgcn_s_barrier();
    __builtin_amdgcn_s_setprio(1);
#pragma unroll
    for (int m = 0; m < 8; ++m) {
      acc[m][0] = mfma16x16(a[m], b0, acc[m][0]);
      acc[m][1] = mfma16x16(a[m], b1, acc[m][1]);
    }
    __builtin_amdgcn_s_setprio(0);
    __builtin_amdgcn_s_barrier();

    // ---- phase B: n-half 1 ----
    b0 = *(const bf16x8*)(bb + (wn * 4 + 2) * 1024 + lane * 16);
    b1 = *(const bf16x8*)(bb + (wn * 4 + 3) * 1024 + lane * 16);
    if (t + 2 < nt) stB(t + 2, nx2);
    __builtin_amdgcn_s_barrier();
    __builtin_amdgcn_s_setprio(1);
#pragma unroll
    for (int m = 0; m < 8; ++m) {
      acc[m][2] = mfma16x16(a[m], b0, acc[m][2]);
      acc[m][3] = mfma16x16(a[m], b1, acc[m][3]);
    }
    __builtin_amdgcn_s_setprio(0);
    if (t + 2 < nt) {
      asm volatile("s_waitcnt vmcnt(4)" ::: "memory");  // t+1 resident, t+2 in flight
    } else {
      asm volatile("s_waitcnt vmcnt(0)" ::: "memory");
    }
    __builtin_amdgcn_s_barrier();

    cur = (cur == 2) ? 0 : cur + 1;
  }

  // ---- epilogue ----  C/D map: col = lane&15, row = (lane>>4)*4 + r
  if (z == 2) {  // V -> vtb[b][d][t]
#pragma unroll
    for (int m = 0; m < 8; ++m)
#pragma unroll
      for (int n = 0; n < 4; ++n)
#pragma unroll
        for (int r = 0; r < 4; ++r) {
          int row = bm + wm * 128 + m * 16 + lhi * 4 + r;
          int col = bn + wn * 64 + n * 16 + l15;
          int bb3 = row >> 11, tt = row & 2047;
          Cv[(size_t)bb3 * 2048 * 2048 + (size_t)col * 2048 + tt] = (bf16)acc[m][n][r];
        }
    return;
  }
  // Q/K: rms-norm over 128-col chunks (two chunks per block), f32 accum
  float* ldsf = (float*)lds;  // [256 rows][4 wn] partials; buffers dead past final barrier
#pragma unroll
  for (int m = 0; m < 8; ++m)
#pragma unroll
    for (int r = 0; r < 4; ++r) {
      float s = acc[m][0][r] * acc[m][0][r] + acc[m][1][r] * acc[m][1][r] +
                acc[m][2][r] * acc[m][2][r] + acc[m][3][r] * acc[m][3][r];
      s += __shfl_xor(s, 1, 64);
      s += __shfl_xor(s, 2, 64);
      s += __shfl_xor(s, 4, 64);
      s += __shfl_xor(s, 8, 64);
      if (l15 == 0) ldsf[(wm * 128 + m * 16 + lhi * 4 + r) * 4 + wn] = s;
    }
  __syncthreads();
  const float osc = (z == 0) ? 0.08838834764831845f : 1.0f;  // fold 1/sqrt(128) into q
  bf16* C = (z == 0) ? Cq : Ck;
#pragma unroll
  for (int m = 0; m < 8; ++m) {
#pragma unroll
    for (int r = 0; r < 4; ++r) {
      int rl = wm * 128 + m * 16 + lhi * 4 + r;
      float tot = ldsf[rl * 4 + (wn & 2)] + ldsf[rl * 4 + (wn & 2) + 1];
      float sc = rsqrtf(tot * (1.0f / 128.0f) + 1.1920929e-07f) * osc;
#pragma unroll
      for (int n = 0; n < 4; ++n) {
        int col = bn + wn * 64 + n * 16 + l15;
        C[(size_t)(bm + rl) * 2048 + col] = (bf16)(acc[m][n][r] * sc);
      }
    }
  }
}

// ---------------- output GEMM (r6 structure): out = (ybuf @ wo^T) * 0.2 ----------------
// 256x128 tile, BK=32, 4 waves (2x2, wave 128x64), 3 buffers x 24KB, 2 blocks/CU.
__global__ __launch_bounds__(256, 2) void gemm_out(const bf16* __restrict__ A, const bf16* __restrict__ B,
                                                   float* __restrict__ Cf) {
  __shared__ char lds[73728];
  const int K = 2048, nt = 64;

  int p = blockIdx.y * gridDim.x + blockIdx.x;
  int lid = (p & 7) * 32 + (p >> 3);  // 256 blocks, bijective
  const int bm = (lid / 16) * 256;
  const int bn = (lid % 16) * 128;

  const int tid = threadIdx.x;
  const int wid = tid >> 6, lane = tid & 63;
  const int l15 = lane & 15, lhi = lane >> 4;
  const int wm = wid >> 1, wn = wid & 1;

  const bf16* aB = A + (size_t)(bm + l15) * K + lhi * 8;
  const bf16* bB = B + (size_t)(bn + l15) * K + lhi * 8;

  auto stage = [&](int t, int pb) {
    char* base = lds + pb * 24576;
    const int k0 = t * 32;
    gload16(aB + (size_t)((0 + wid) * 16) * K + k0, base + wid * 1024);
    gload16(aB + (size_t)((4 + wid) * 16) * K + k0, base + 4096 + wid * 1024);
    gload16(aB + (size_t)((8 + wid) * 16) * K + k0, base + 8192 + wid * 1024);
    gload16(aB + (size_t)((12 + wid) * 16) * K + k0, base + 12288 + wid * 1024);
    gload16(bB + (size_t)((0 + wid) * 16) * K + k0, base + 16384 + wid * 1024);
    gload16(bB + (size_t)((4 + wid) * 16) * K + k0, base + 20480 + wid * 1024);
  };

  const f32x4 fz = {0.f, 0.f, 0.f, 0.f};
  f32x4 acc[8][4];
#pragma unroll
  for (int m = 0; m < 8; ++m)
#pragma unroll
    for (int n = 0; n < 4; ++n) acc[m][n] = fz;

  stage(0, 0);
  stage(1, 1);
  asm volatile("s_waitcnt vmcnt(6)" ::: "memory");
  __builtin_amdgcn_s_barrier();

  for (int t = 0; t < nt; ++t) {
    const char* ab = lds + (t % 3) * 24576;
    if (t + 2 < nt) stage(t + 2, (t + 2) % 3);
    bf16x8 a[8], b[4];
#pragma unroll
    for (int m = 0; m < 8; ++m)
      a[m] = *(const bf16x8*)(ab + (wm * 8 + m) * 1024 + lane * 16);
#pragma unroll
    for (int n = 0; n < 4; ++n)
      b[n] = *(const bf16x8*)(ab + 16384 + (wn * 4 + n) * 1024 + lane * 16);
    __builtin_amdgcn_s_setprio(1);
#pragma unroll
    for (int m = 0; m < 8; ++m)
#pragma unroll
      for (int n = 0; n < 4; ++n) acc[m][n] = mfma16x16(a[m], b[n], acc[m][n]);
    __builtin_amdgcn_s_setprio(0);
    if (t + 2 < nt) {
      asm volatile("s_waitcnt vmcnt(6)" ::: "memory");
    } else {
      asm volatile("s_waitcnt vmcnt(0)" ::: "memory");
    }
    __builtin_amdgcn_s_barrier();
  }

#pragma unroll
  for (int m = 0; m < 8; ++m)
#pragma unroll
    for (int n = 0; n < 4; ++n)
#pragma unroll
      for (int r = 0; r < 4; ++r) {
        int row = bm + wm * 128 + m * 16 + lhi * 4 + r;
        int col = bn + wn * 64 + n * 16 + l15;
        Cf[(size_t)row * 2048 + col] = acc[m][n][r] * 0.2f;
      }
}

// ---------------- dual-stream causal flash attention ----------------
__global__ __launch_bounds__(256) void attn_kernel(const bf16* __restrict__ qb, const bf16* __restrict__ kb,
                                                   const bf16* __restrict__ vtb, bf16* __restrict__ yb,
                                                   const float* __restrict__ lamp) {
  __shared__ char lds[53248];
  const int tid = threadIdx.x;
  const int wid = tid >> 6, lane = tid & 63;
  const int l15 = lane & 15, lhi = lane >> 4;
  char* vtl = lds + 32768;
  char* pbf = lds + 49152 + wid * 1024;
  const int qt = 31 - blockIdx.y;
  const int bh = blockIdx.x;
  const int b = bh >> 3, h = bh & 7;
  const int qr0 = qt * 64 + wid * 16;
  const float lam = lamp[0];

  const bf16* qrow = qb + (size_t)(b * 2048 + qr0 + l15) * 2048 + h * 256 + lhi * 8;
  bf16x8 q1f[4], q2f[4];
#pragma unroll
  for (int s = 0; s < 4; ++s) {
    q1f[s] = *(const bf16x8*)(qrow + s * 32);
    q2f[s] = *(const bf16x8*)(qrow + 128 + s * 32);
  }

  const f32x4 fz = {0.f, 0.f, 0.f, 0.f};
  f32x4 y1[16], y2[16];
#pragma unroll
  for (int f = 0; f < 16; ++f) { y1[f] = fz; y2[f] = fz; }
  float l1[4] = {0.f, 0.f, 0.f, 0.f}, l2[4] = {0.f, 0.f, 0.f, 0.f};

  const int nkt = 2 * qt + 2;
  const bf16* kbase = kb + (size_t)(b * 2048) * 2048 + h * 256;
  const bf16* vbase = vtb + (size_t)b * 2048 * 2048 + (size_t)(h * 256) * 2048;

  auto stageK = [&](int kt2, int p) {
    const int t0 = kt2 * 32;
    char* kd = lds + p * 16384 + wid * 1024;
    const bf16* sp = kbase + (size_t)(t0 + l15) * 2048 + wid * 32 + lhi * 8;
    gload16(sp, kd);
    gload16(sp + 16 * 2048, kd + 4096);
    gload16(sp + 128, kd + 8192);
    gload16(sp + 16 * 2048 + 128, kd + 12288);
  };
  auto stageVT = [&](int kt2) {
    const int t0 = kt2 * 32;
    const bf16* vp = vbase + (size_t)(wid * 16 + l15) * 2048 + t0 + lhi * 8;
#pragma unroll
    for (int i = 0; i < 4; ++i)
      gload16(vp + (size_t)i * 64 * 2048, vtl + (i * 4 + wid) * 1024);
  };

  stageK(0, 0);
  stageVT(0);
  __syncthreads();

  for (int kt = 0; kt < nkt; ++kt) {
    const int cur = kt & 1;
    const int t0 = kt * 32;
    const bool active = (t0 <= qr0 + 15);
    f32x4 s1g[2], s2g[2];
    if (active) {
      const char* kc = lds + cur * 16384;
#pragma unroll
      for (int g = 0; g < 2; ++g) {
        f32x4 a1 = fz, a2 = fz;
#pragma unroll
        for (int s = 0; s < 4; ++s) {
          a1 = mfma16x16(q1f[s], *(const bf16x8*)(kc + ((g * 4 + s) * 64 + lane) * 16), a1);
          a2 = mfma16x16(q2f[s], *(const bf16x8*)(kc + 8192 + ((g * 4 + s) * 64 + lane) * 16), a2);
        }
        s1g[g] = a1;
        s2g[g] = a2;
      }
      if (t0 + 31 > qr0) {
#pragma unroll
        for (int g = 0; g < 2; ++g) {
          int col = t0 + g * 16 + l15;
#pragma unroll
          for (int r = 0; r < 4; ++r) {
            int row = qr0 + lhi * 4 + r;
            if (col > row) { s1g[g][r] = -1e30f; s2g[g][r] = -1e30f; }
          }
        }
      }
#pragma unroll
      for (int g = 0; g < 2; ++g) {
#pragma unroll
        for (int r = 0; r < 4; ++r) {
          float p1 = __expf(s1g[g][r] - 12.0f);
          float p2 = __expf(s2g[g][r] - 12.0f);
          l1[r] += p1;
          l2[r] += p2;
          *(bf16*)(pbf + ((lhi * 4 + r) * 32 + g * 16 + l15) * 2) = (bf16)p1;
          s2g[g][r] = p2;
        }
      }
    }
    __syncthreads();
    if (active) {
      bf16x8 pa1 = *(const bf16x8*)(pbf + (l15 * 32 + lhi * 8) * 2);
#pragma unroll
      for (int f = 0; f < 16; ++f)
        y1[f] = mfma16x16(pa1, *(const bf16x8*)(vtl + (f * 64 + lane) * 16), y1[f]);
#pragma unroll
      for (int g = 0; g < 2; ++g)
#pragma unroll
        for (int r = 0; r < 4; ++r)
          *(bf16*)(pbf + ((lhi * 4 + r) * 32 + g * 16 + l15) * 2) = (bf16)s2g[g][r];
      bf16x8 pa2 = *(const bf16x8*)(pbf + (l15 * 32 + lhi * 8) * 2);
#pragma unroll
      for (int f = 0; f < 16; ++f)
        y2[f] = mfma16x16(pa2, *(const bf16x8*)(vtl + (f * 64 + lane) * 16), y2[f]);
    }
    __syncthreads();
    if (kt + 1 < nkt) {
      stageK(kt + 1, cur ^ 1);
      stageVT(kt + 1);
    }
  }

#pragma unroll
  for (int r = 0; r < 4; ++r) {
    float s1 = l1[r], s2 = l2[r];
#pragma unroll
    for (int m = 1; m <= 8; m <<= 1) {
      s1 += __shfl_xor(s1, m, 64);
      s2 += __shfl_xor(s2, m, 64);
    }
    float inv1 = 1.f / s1;
    float inv2 = lam / s2;
    int row = qr0 + lhi * 4 + r;
    bf16* orow = yb + (size_t)(b * 2048 + row) * 2048 + h * 256 + l15;
#pragma unroll
    for (int f = 0; f < 16; ++f) {
      float v = y1[f][r] * inv1 - y2[f][r] * inv2;
      orow[f * 16] = (bf16)v;
    }
  }
}

// ---------------------------------------------------------------------------
extern "C" void kernel_launch(void* const* d_in, const int* in_sizes, int n_in,
                              void* d_out, int out_size, void* d_ws, size_t ws_size,
                              hipStream_t stream) {
  const float* x = (const float*)d_in[0];
  const float* wq = (const float*)d_in[1];
  const float* wk = (const float*)d_in[2];
  const float* wv = (const float*)d_in[3];
  const float* wo = (const float*)d_in[4];
  const float* lq1 = (const float*)d_in[5];
  const float* lk1 = (const float*)d_in[6];
  const float* lq2 = (const float*)d_in[7];
  const float* lk2 = (const float*)d_in[8];
  float* out = (float*)d_out;
  char* ws = (char*)d_ws;

  if (ws_size < 117440516) return;

  bf16* xb = (bf16*)(ws + 0);             // [4096][2048]
  bf16* wqb = (bf16*)(ws + 16777216);     // [2048][2048]
  bf16* wkb = (bf16*)(ws + 25165824);
  bf16* wvb = (bf16*)(ws + 33554432);
  bf16* wob = (bf16*)(ws + 41943040);
  bf16* qbuf = (bf16*)(ws + 50331648);    // [4096][2048]
  bf16* kbuf = (bf16*)(ws + 67108864);    // [4096][2048]
  bf16* vtb = (bf16*)(ws + 83886080);     // [2][2048 d][2048 t]
  bf16* ybuf = (bf16*)(ws + 100663296);   // [4096][2048]
  float* lam = (float*)(ws + 117440512);

  cast_f32_bf16<<<8192, 256, 0, stream>>>(x, xb, 2097152);
  cast4_w<<<dim3(4096, 4), 256, 0, stream>>>(wq, wk, wv, wo, wqb, wkb, wvb, wob);
  lambda_kernel<<<1, 256, 0, stream>>>(lq1, lk1, lq2, lk2, lam);

  gemm_qkv8<<<dim3(24, 16), 512, 0, stream>>>(xb, wqb, wkb, wvb, qbuf, kbuf, vtb);

  attn_kernel<<<dim3(16, 32), 256, 0, stream>>>(qbuf, kbuf, vtb, ybuf, lam);

  gemm_out<<<dim3(16, 16), 256, 0, stream>>>(ybuf, wob, out);
}